// Round 1
// 352.857 us; speedup vs baseline: 1.0563x; 1.0563x over previous
//
#include <hip/hip_runtime.h>

typedef unsigned short ushort_t;
typedef __bf16 bf16x8 __attribute__((ext_vector_type(8)));
typedef float f32x4 __attribute__((ext_vector_type(4)));
typedef unsigned int u32x4 __attribute__((ext_vector_type(4)));
typedef unsigned short us4 __attribute__((ext_vector_type(4)));
typedef unsigned short us8 __attribute__((ext_vector_type(8)));

#define DEVINL __device__ __forceinline__

DEVINL ushort_t f2bf(float f) {
    unsigned u = __float_as_uint(f);
    u += 0x7FFF + ((u >> 16) & 1);   // RNE
    return (ushort_t)(u >> 16);
}
DEVINL float bf2f(ushort_t h) { return __uint_as_float(((unsigned)h) << 16); }

DEVINL void gload_lds16(const void* g, void* l) {
    __builtin_amdgcn_global_load_lds(
        (const __attribute__((address_space(1))) void*)g,
        (__attribute__((address_space(3))) void*)l, 16, 0, 0);
}

DEVINL bf16x8 ld_frag(const ushort_t* p) {
    us8 v = *(const us8*)p;
    return __builtin_bit_cast(bf16x8, v);
}

#define BAR()     asm volatile("s_barrier" ::: "memory")
#define LGKM0()   asm volatile("s_waitcnt lgkmcnt(0)" ::: "memory")
#define VMCNT(n)  asm volatile("s_waitcnt vmcnt(" #n ")" ::: "memory")

// Raw barrier with fine-grained vmcnt for flash_attn.
#define BARRIER_KEEP4()  asm volatile("s_waitcnt vmcnt(4)\n\ts_barrier" ::: "memory")
#define BARRIER_KEEP8()  asm volatile("s_waitcnt vmcnt(8)\n\ts_barrier" ::: "memory")
#define BARRIER_KEEP0()  asm volatile("s_waitcnt vmcnt(0)\n\ts_barrier" ::: "memory")

// ---------------------------------------------------------------- fused convert
__global__ __launch_bounds__(256) void convert_all(const f32x4* __restrict__ h,
                                                   const f32x4* __restrict__ qw,
                                                   const f32x4* __restrict__ kw,
                                                   const f32x4* __restrict__ vw,
                                                   const f32x4* __restrict__ ow,
                                                   us4* __restrict__ hb,
                                                   us4* __restrict__ wqkv,
                                                   us4* __restrict__ owb) {
    const int N0 = 2097152;              // hidden  (2*2048*2048 /4)
    const int N1 = 1048576;              // q_w     (2048*2048 /4)
    const int N2 = 524288;               // k_w
    const int N3 = 524288;               // v_w
    int i = blockIdx.x * 256 + threadIdx.x;
    const f32x4* src; us4* dst;
    if (i < N0)                               { src = h  + i;                 dst = hb + i; }
    else if ((i -= N0) < N1)                  { src = qw + i;                 dst = wqkv + i; }
    else if ((i -= N1) < N2)                  { src = kw + i;                 dst = wqkv + 1048576 + i; }
    else if ((i -= N2) < N3)                  { src = vw + i;                 dst = wqkv + 1572864 + i; }
    else                                      { i -= N3; src = ow + i;       dst = owb + i; }
    f32x4 f = *src;
    us4 o;
    o[0] = f2bf(f[0]); o[1] = f2bf(f[1]); o[2] = f2bf(f[2]); o[3] = f2bf(f[3]);
    *dst = o;
}

// ---------------------------------------------------------------- GEMM C = A @ W^T
// 256x256 tile, BK=64, 8 waves (2x4), 8-phase schedule (T2+T3+T4+T5).
// A[4096][K] bf16, W[N][K] bf16, C[4096][N]. Requires N in {4096, 2048},
// K % 128 == 0. Grid = (4096/256) * (N/256) blocks of 512 threads.
// LDS: 2 double-buffers x (256x64) for A and B = 128 KiB -> 1 block/CU.
// Stage stream per K-tile t: P1:A1(t+1) P2:B0(t+2) P3:B1(t+2) P4:A0(t+2),
// vmcnt(6) only at P4 (3 half-tiles stay in flight across barriers).
// Swizzle: 16B-granule XOR with (row&7), applied to the global source on the
// staging side (LDS dest stays linear for global_load_lds) and to the
// ds_read_b128 address on the fragment side -> conflict-free reads.
template <typename OutT>
__global__ __launch_bounds__(512, 2) void gemm256(const ushort_t* __restrict__ A,
                                                  const ushort_t* __restrict__ W,
                                                  OutT* __restrict__ C,
                                                  int N, int K) {
    __shared__ ushort_t As[2][256 * 64];
    __shared__ ushort_t Bs[2][256 * 64];
    const int t = threadIdx.x;
    const int lane = t & 63;
    const int quad = lane >> 4, l16 = lane & 15;
    const int wm = t >> 8, wn = (t >> 6) & 3;        // 2 x 4 wave grid

    // XCD-aware tile mapping (bijective: grid % 8 == 0 in both shapes)
    int bid = blockIdx.x;
    int xcd = bid & 7, j = bid >> 3;
    int tm, tn;
    if (N == 4096) { tm = (xcd >> 1) * 4 + (j >> 3); tn = (xcd & 1) * 8 + (j & 7); }
    else           { tm = xcd * 2 + (j >> 3);        tn = j & 7; }
    const int bm = tm * 256, bn = tn * 256;

    // staging geometry: one 128x64 half-tile = 2 x 16B per thread, linear LDS
    const int srow0 = t >> 3;                        // rows 0..63
    const int sg0 = ((t & 7) ^ (srow0 & 7)) * 8;     // inverse-swizzled src col
    const int srow1 = srow0 + 64;                    // rows 64..127
    const int sg1 = ((t & 7) ^ (srow1 & 7)) * 8;

    auto stageA = [&](int buf, int half, int k0) {
        gload_lds16(A + (size_t)(bm + half * 128 + srow0) * K + k0 + sg0,
                    &As[buf][half * 8192 + t * 8]);
        gload_lds16(A + (size_t)(bm + half * 128 + srow1) * K + k0 + sg1,
                    &As[buf][half * 8192 + 4096 + t * 8]);
    };
    auto stageB = [&](int buf, int half, int k0) {
        gload_lds16(W + (size_t)(bn + half * 128 + srow0) * K + k0 + sg0,
                    &Bs[buf][half * 8192 + t * 8]);
        gload_lds16(W + (size_t)(bn + half * 128 + srow1) * K + k0 + sg1,
                    &Bs[buf][half * 8192 + 4096 + t * 8]);
    };

    // fragment reads: row = base + frag*16 + l16 (frag*16 = 0 mod 8, so the
    // swizzle XOR reduces to l16&7, constant per lane)
    const int xsw = l16 & 7;
    const int arow = (wm * 128 + l16) * 64;
    const int brow = (wn * 64 + l16) * 64;
    const int ac0 = ((0 + quad) ^ xsw) * 8;          // kk=0 granule offset
    const int ac1 = ((4 + quad) ^ xsw) * 8;          // kk=1

    auto ldA = [&](int buf, int mf, int kk) {
        return ld_frag(&As[buf][arow + mf * 1024 + (kk ? ac1 : ac0)]);
    };
    auto ldB = [&](int buf, int nf, int kk) {
        return ld_frag(&Bs[buf][brow + nf * 1024 + (kk ? ac1 : ac0)]);
    };

    f32x4 acc[8][4];
#pragma unroll
    for (int i = 0; i < 8; i++)
#pragma unroll
        for (int jj = 0; jj < 4; jj++) acc[i][jj] = f32x4{0.f, 0.f, 0.f, 0.f};

    const int NIT = K >> 6;
    // prologue: tile0 complete + tile1 {B0,B1,A0} in flight (3 half-tiles)
    stageA(0, 0, 0); stageA(0, 1, 0); stageB(0, 0, 0); stageB(0, 1, 0);
    VMCNT(4);
    stageB(1, 0, 64); stageB(1, 1, 64); stageA(1, 0, 64);
    VMCNT(6);
    BAR();

    bf16x8 a[4][2], b[4][2];
    for (int tt = 0; tt < NIT; ++tt) {
        const int buf = tt & 1;
        const int k2 = (tt + 2) << 6;

        // ---- phase 1: quadrant (m-lo, n-lo). Read A-lo (8) + all B (8).
#pragma unroll
        for (int mt = 0; mt < 4; mt++) { a[mt][0] = ldA(buf, mt, 0); a[mt][1] = ldA(buf, mt, 1); }
#pragma unroll
        for (int nt = 0; nt < 4; nt++) { b[nt][0] = ldB(buf, nt, 0); b[nt][1] = ldB(buf, nt, 1); }
        if (tt + 1 < NIT) stageA(buf ^ 1, 1, (tt + 1) << 6);
        BAR(); LGKM0();
        __builtin_amdgcn_s_setprio(1);
#pragma unroll
        for (int mt = 0; mt < 4; mt++)
#pragma unroll
            for (int nt = 0; nt < 2; nt++)
#pragma unroll
                for (int kk = 0; kk < 2; kk++)
                    acc[mt][nt] = __builtin_amdgcn_mfma_f32_16x16x32_bf16(a[mt][kk], b[nt][kk], acc[mt][nt], 0, 0, 0);
        __builtin_amdgcn_s_setprio(0);
        LGKM0();                 // drain b-hi reads so P2's stage can't race
        BAR();

        // ---- phase 2: (m-lo, n-hi). B0 region fully consumed in P1.
        if (tt + 2 < NIT) stageB(buf, 0, k2);
        BAR();
        __builtin_amdgcn_s_setprio(1);
#pragma unroll
        for (int mt = 0; mt < 4; mt++)
#pragma unroll
            for (int nt = 0; nt < 2; nt++)
#pragma unroll
                for (int kk = 0; kk < 2; kk++)
                    acc[mt][2 + nt] = __builtin_amdgcn_mfma_f32_16x16x32_bf16(a[mt][kk], b[2 + nt][kk], acc[mt][2 + nt], 0, 0, 0);
        __builtin_amdgcn_s_setprio(0);
        BAR();

        // ---- phase 3: (m-hi, n-lo). Read A-hi (8).
#pragma unroll
        for (int mt = 0; mt < 4; mt++) { a[mt][0] = ldA(buf, 4 + mt, 0); a[mt][1] = ldA(buf, 4 + mt, 1); }
        if (tt + 2 < NIT) stageB(buf, 1, k2);
        BAR(); LGKM0();
        __builtin_amdgcn_s_setprio(1);
#pragma unroll
        for (int mt = 0; mt < 4; mt++)
#pragma unroll
            for (int nt = 0; nt < 2; nt++)
#pragma unroll
                for (int kk = 0; kk < 2; kk++)
                    acc[4 + mt][nt] = __builtin_amdgcn_mfma_f32_16x16x32_bf16(a[mt][kk], b[nt][kk], acc[4 + mt][nt], 0, 0, 0);
        __builtin_amdgcn_s_setprio(0);
        BAR();

        // ---- phase 4: (m-hi, n-hi). A0 region consumed by end of P3.
        if (tt + 2 < NIT)      { stageA(buf, 0, k2); VMCNT(6); }  // keep 3 halves
        else if (tt + 1 < NIT) { VMCNT(0); }                      // final drain
        BAR();
        __builtin_amdgcn_s_setprio(1);
#pragma unroll
        for (int mt = 0; mt < 4; mt++)
#pragma unroll
            for (int nt = 0; nt < 2; nt++)
#pragma unroll
                for (int kk = 0; kk < 2; kk++)
                    acc[4 + mt][2 + nt] = __builtin_amdgcn_mfma_f32_16x16x32_bf16(a[mt][kk], b[2 + nt][kk], acc[4 + mt][2 + nt], 0, 0, 0);
        __builtin_amdgcn_s_setprio(0);
        BAR();
    }

    // epilogue
#pragma unroll
    for (int mf = 0; mf < 8; mf++)
#pragma unroll
        for (int nf = 0; nf < 4; nf++) {
            const int row = bm + wm * 128 + mf * 16 + quad * 4;
            const int col = bn + wn * 64 + nf * 16 + l16;
#pragma unroll
            for (int rr = 0; rr < 4; rr++) {
                float v = acc[mf][nf][rr];
                if constexpr (sizeof(OutT) == 2)
                    C[(size_t)(row + rr) * N + col] = (OutT)f2bf(v);
                else
                    C[(size_t)(row + rr) * N + col] = v;
            }
        }
}

// ---------------------------------------------------------------- RoPE + l2norm
__global__ __launch_bounds__(256) void rope_norm(const ushort_t* __restrict__ qkv,
                                                 const float* __restrict__ cosb,
                                                 const float* __restrict__ sinb,
                                                 ushort_t* __restrict__ q,
                                                 ushort_t* __restrict__ k) {
    int row = blockIdx.x;                 // b*2048 + s
    int b = row >> 11, s = row & 2047;
    int w = threadIdx.x >> 6, lane = threadIdx.x & 63;
    int hh = blockIdx.y * 4 + w;          // 0..23
    const ushort_t* src = qkv + (size_t)row * 4096 + hh * 128;
    float x1 = bf2f(src[lane]);
    float x2 = bf2f(src[lane + 64]);
    float c = cosb[(size_t)row * 128 + lane];
    float sn = sinb[(size_t)row * 128 + lane];
    float y1 = x1 * c + x2 * sn;
    float y2 = x2 * c - x1 * sn;
    float ss = y1 * y1 + y2 * y2;
#pragma unroll
    for (int off = 1; off < 64; off <<= 1) ss += __shfl_xor(ss, off);
    float rinv = rsqrtf(ss * (1.0f / 128.0f) + 1e-6f);
    y1 *= rinv; y2 *= rinv;
    ushort_t* dst;
    if (hh < 16) dst = q + (((size_t)(b * 16 + hh)) * 2048 + s) * 128;
    else         dst = k + (((size_t)(b * 8 + hh - 16)) * 2048 + s) * 128;
    dst[lane] = f2bf(y1);
    dst[lane + 64] = f2bf(y2);
}

// ---------------------------------------------------------------- V transpose
__global__ __launch_bounds__(256) void v_transpose(const ushort_t* __restrict__ qkv,
                                                   ushort_t* __restrict__ vt) {
    __shared__ ushort_t tile[64 * 72];
    int t = threadIdx.x;
    int s0 = blockIdx.x * 64, d0 = blockIdx.y * 64, bh = blockIdx.z;
    int b = bh >> 3, kvh = bh & 7;
    {
        int sl = t >> 2, c = t & 3;
        const ushort_t* src = qkv + (size_t)(b * 2048 + s0 + sl) * 4096 + 3072 + kvh * 128 + d0 + c * 16;
        u32x4 v0 = *(const u32x4*)src;
        u32x4 v1 = *(const u32x4*)(src + 8);
        *(u32x4*)&tile[sl * 72 + c * 16] = v0;
        *(u32x4*)&tile[sl * 72 + c * 16 + 8] = v1;
    }
    __syncthreads();
    {
        int dl = t >> 2, c = t & 3;
        alignas(16) ushort_t tmp[16];
#pragma unroll
        for (int i = 0; i < 16; i++) tmp[i] = tile[(c * 16 + i) * 72 + dl];
        ushort_t* dst = vt + (size_t)(bh * 128 + d0 + dl) * 2048 + s0 + c * 16;
        *(u32x4*)dst = *(const u32x4*)&tmp[0];
        *(u32x4*)(dst + 8) = *(const u32x4*)&tmp[8];
    }
}

// ---------------------------------------------------------------- Flash attention
// (GQA-merged, fixed-max, paired q-tiles, TRIPLE-buffered distance-2 async
//  staging with vmcnt(8) barriers). 1D grid of 256 blocks, 1 block/CU.
__global__ __launch_bounds__(256) void flash_attn(const ushort_t* __restrict__ q,
                                                  const ushort_t* __restrict__ k,
                                                  const ushort_t* __restrict__ vt,
                                                  ushort_t* __restrict__ attn) {
    __shared__ ushort_t Ks[3][4 * 64 * 32];      // 3 x 16 KB  [qd][64][32]
    __shared__ ushort_t Vts[3][2 * 128 * 32];    // 3 x 16 KB  [ks][128][32]
    __shared__ ushort_t Ps[4 * 32 * 72];         // 18 KB per-wave scratch
    const int t = threadIdx.x;
    const int w = t >> 6, lane = t & 63;
    const int quad = lane >> 4, l16 = lane & 15;
    const int sw = (l16 >> 1) & 3;
    const int lid = blockIdx.x;
    const int xcd = lid & 7, jj = lid >> 3;
    const int g = xcd * 2 + (jj >> 4);           // (b,kvh) group, 2 per XCD
    const int p = jj & 15;                       // q-tile pair index 0..15
    const int b = g >> 3, kvh = g & 7;
    const int h0 = kvh * 2;
    const size_t kbase = ((size_t)(b * 8 + kvh)) * 2048 * 128;
    const size_t vbase = ((size_t)(b * 8 + kvh)) * 128 * 2048;

    const float C1 = 0.12751744f;   // (1/sqrt(128)) * log2(e)
    const float C2 = 1.45f;         // fixed max in log2 domain

    auto stage = [&](int j0, int buf) {
#pragma unroll
        for (int i = 0; i < 4; i++) {            // K tile (16KB), k-blocked
            int u = i * 256 + t;
            int qd = u >> 8, rr = (u >> 2) & 63;
            int c4 = ((u & 3) ^ ((rr >> 1) & 3)) * 8;
            gload_lds16(k + kbase + (size_t)(j0 + rr) * 128 + qd * 32 + c4,
                        (char*)Ks[buf] + u * 16);
        }
#pragma unroll
        for (int i = 0; i < 4; i++) {            // Vt tile (16KB), k-blocked
            int u = i * 256 + t;
            int ks = u >> 9, dd = (u >> 2) & 127;
            int c4 = ((u & 3) ^ ((dd >> 1) & 3)) * 8;
            gload_lds16(vt + vbase + (size_t)dd * 2048 + j0 + ks * 32 + c4,
                        (char*)Vts[buf] + u * 16);
        }
    };

    const int qtile0 = 31 - p;                   // heavy pass first
    const int S_total = qtile0 + 1 + p + 1;      // tile-stream length (=33)
    auto j0_of = [&](int s) { return (s <= qtile0 ? s : s - qtile0 - 1) * 64; };

    stage(j0_of(0), 0);
    stage(j0_of(1), 1);
    int sidx = 0, cb = 0, pb = 2;

    for (int pass = 0; pass < 2; ++pass) {
        const int qi = pass ? p : qtile0;
        const int q0 = qi * 64;

        bf16x8 qf[2][4];
#pragma unroll
        for (int h = 0; h < 2; h++) {
            const size_t qbase = ((size_t)(b * 16 + h0 + h) * 2048 + q0 + w * 16 + l16) * 128;
#pragma unroll
            for (int qd = 0; qd < 4; qd++) {
                us8 v = *(const us8*)(q + qbase + qd * 32 + quad * 8);
                qf[h][qd] = __builtin_bit_cast(bf16x8, v);
            }
        }

        f32x4 o[2][8];
#pragma unroll
        for (int h = 0; h < 2; h++)
#pragma unroll
            for (int i = 0; i < 8; i++) o[h][i] = f32x4{0.f, 0.f, 0.f, 0.f};
        float lsum[2][4];
#pragma unroll
        for (int h = 0; h < 2; h++)
#pragma unroll
            for (int r = 0; r < 4; r++) lsum[h][r] = 0.f;

        for (int jt = 0; jt <= qi; ++jt) {
            const int j0 = jt * 64;
            const bool diag = (jt == qi);
            if (sidx + 1 < S_total) BARRIER_KEEP8();   // drain tile sidx, keep sidx+1
            else                    BARRIER_KEEP0();
            if (sidx + 2 < S_total) stage(j0_of(sidx + 2), pb);
            const ushort_t* Kb = Ks[cb];
            const ushort_t* Vb = Vts[cb];
            cb = cb == 2 ? 0 : cb + 1;
            pb = pb == 2 ? 0 : pb + 1;
            sidx++;

            // S = Q K^T for both heads; each kf feeds 2 MFMAs
            f32x4 sc[2][4];
#pragma unroll
            for (int h = 0; h < 2; h++)
#pragma unroll
                for (int c = 0; c < 4; c++) sc[h][c] = f32x4{0.f, 0.f, 0.f, 0.f};
#pragma unroll
            for (int c = 0; c < 4; c++)
#pragma unroll
                for (int qd = 0; qd < 4; qd++) {
                    bf16x8 kf = ld_frag(&Kb[qd * 2048 + (c * 16 + l16) * 32 + (quad ^ sw) * 8]);
                    sc[0][c] = __builtin_amdgcn_mfma_f32_16x16x32_bf16(qf[0][qd], kf, sc[0][c], 0, 0, 0);
                    sc[1][c] = __builtin_amdgcn_mfma_f32_16x16x32_bf16(qf[1][qd], kf, sc[1][c], 0, 0, 0);
                }

            // p = exp2(s*C1 - C2); mask only on the diagonal tile
#pragma unroll
            for (int c = 0; c < 4; c++)
#pragma unroll
                for (int r = 0; r < 4; r++) {
                    float p0 = __builtin_amdgcn_exp2f(sc[0][c][r] * C1 - C2);
                    float p1 = __builtin_amdgcn_exp2f(sc[1][c][r] * C1 - C2);
                    if (diag) {
                        int kg = j0 + c * 16 + l16;
                        int qg = q0 + w * 16 + quad * 4 + r;
                        if (kg > qg) { p0 = 0.f; p1 = 0.f; }
                    }
                    lsum[0][r] += p0;
                    lsum[1][r] += p1;
                    Ps[w * 2304 + (quad * 4 + r) * 72 + c * 16 + l16] = f2bf(p0);
                    Ps[w * 2304 + (16 + quad * 4 + r) * 72 + c * 16 + l16] = f2bf(p1);
                }

            // O += P V; each vf feeds 2 MFMAs
#pragma unroll
            for (int ks = 0; ks < 2; ks++) {
                bf16x8 pf0 = ld_frag(&Ps[w * 2304 + l16 * 72 + ks * 32 + quad * 8]);
                bf16x8 pf1 = ld_frag(&Ps[w * 2304 + (16 + l16) * 72 + ks * 32 + quad * 8]);
#pragma unroll
                for (int od = 0; od < 8; od++) {
                    bf16x8 vf = ld_frag(&Vb[ks * 4096 + (od * 16 + l16) * 32 + (quad ^ sw) * 8]);
                    o[0][od] = __builtin_amdgcn_mfma_f32_16x16x32_bf16(pf0, vf, o[0][od], 0, 0, 0);
                    o[1][od] = __builtin_amdgcn_mfma_f32_16x16x32_bf16(pf1, vf, o[1][od], 0, 0, 0);
                }
            }
        }

        // epilogue for this q-tile
        float rl[2][4];
#pragma unroll
        for (int h = 0; h < 2; h++)
#pragma unroll
            for (int r = 0; r < 4; r++) {
                float s = lsum[h][r];
#pragma unroll
                for (int off = 1; off < 16; off <<= 1) s += __shfl_xor(s, off);
                rl[h][r] = 1.0f / s;
            }
#pragma unroll
        for (int h = 0; h < 2; h++) {
            const size_t obase = ((size_t)(b * 2048 + q0 + w * 16 + quad * 4)) * 2048 + (h0 + h) * 128;
#pragma unroll
            for (int od = 0; od < 8; od++)
#pragma unroll
                for (int r = 0; r < 4; r++)
                    attn[obase + (size_t)r * 2048 + od * 16 + l16] = f2bf(o[h][od][r] * rl[h][r]);
        }
    }
}

// ---------------------------------------------------------------- launch
extern "C" void kernel_launch(void* const* d_in, const int* in_sizes, int n_in,
                              void* d_out, int out_size, void* d_ws, size_t ws_size,
                              hipStream_t stream) {
    (void)in_sizes; (void)n_in; (void)out_size; (void)ws_size;
    const float* hidden = (const float*)d_in[0];
    const float* cosb   = (const float*)d_in[1];
    const float* sinb   = (const float*)d_in[2];
    // d_in[3] = attention_mask: causal, computed inline
    const float* q_w    = (const float*)d_in[4];
    const float* k_w    = (const float*)d_in[5];
    const float* v_w    = (const float*)d_in[6];
    const float* o_w    = (const float*)d_in[7];

    char* ws = (char*)d_ws;                                  // 104 MB used
    ushort_t* hb   = (ushort_t*)(ws);                        // [4096][2048] bf16 hidden
    ushort_t* wqkv = (ushort_t*)(ws + (16ull << 20));        // [4096][2048] bf16 q|k|v weights
    ushort_t* owb  = (ushort_t*)(ws + (32ull << 20));        // [2048][2048] bf16 o_w
    ushort_t* qkv  = (ushort_t*)(ws + (40ull << 20));        // [4096][4096] bf16 qkv proj
    ushort_t* attn = qkv;                                    // alias: qkv consumed before flash
    ushort_t* qb   = (ushort_t*)(ws + (72ull << 20));        // [2][16][2048][128]
    ushort_t* kb   = (ushort_t*)(ws + (88ull << 20));        // [2][8][2048][128]
    ushort_t* vt   = (ushort_t*)(ws + (96ull << 20));        // [2][8][128][2048]

    convert_all<<<20480, 256, 0, stream>>>((const f32x4*)hidden, (const f32x4*)q_w,
                                           (const f32x4*)k_w, (const f32x4*)v_w,
                                           (const f32x4*)o_w,
                                           (us4*)hb, (us4*)wqkv, (us4*)owb);

    gemm256<ushort_t><<<256, 512, 0, stream>>>(hb, wqkv, qkv, 4096, 2048);
    rope_norm<<<dim3(4096, 6), 256, 0, stream>>>(qkv, cosb, sinb, qb, kb);
    v_transpose<<<dim3(32, 2, 16), 256, 0, stream>>>(qkv, vt);
    flash_attn<<<256, 256, 0, stream>>>(qb, kb, vt, attn);
    gemm256<float><<<128, 512, 0, stream>>>(attn, owb, (float*)d_out, 2048, 2048);
}

// Round 3
// 349.759 us; speedup vs baseline: 1.0657x; 1.0089x over previous
//
#include <hip/hip_runtime.h>

typedef unsigned short ushort_t;
typedef __bf16 bf16x8 __attribute__((ext_vector_type(8)));
typedef float f32x4 __attribute__((ext_vector_type(4)));
typedef unsigned int u32x4 __attribute__((ext_vector_type(4)));
typedef unsigned short us4 __attribute__((ext_vector_type(4)));
typedef unsigned short us8 __attribute__((ext_vector_type(8)));

#define DEVINL __device__ __forceinline__

DEVINL ushort_t f2bf(float f) {
    unsigned u = __float_as_uint(f);
    u += 0x7FFF + ((u >> 16) & 1);   // RNE
    return (ushort_t)(u >> 16);
}
DEVINL float bf2f(ushort_t h) { return __uint_as_float(((unsigned)h) << 16); }

DEVINL void gload_lds16(const void* g, void* l) {
    __builtin_amdgcn_global_load_lds(
        (const __attribute__((address_space(1))) void*)g,
        (__attribute__((address_space(3))) void*)l, 16, 0, 0);
}

DEVINL bf16x8 ld_frag(const ushort_t* p) {
    us8 v = *(const us8*)p;
    return __builtin_bit_cast(bf16x8, v);
}

#define BAR()     asm volatile("s_barrier" ::: "memory")
#define LGKM0()   asm volatile("s_waitcnt lgkmcnt(0)" ::: "memory")
#define VMCNT(n)  asm volatile("s_waitcnt vmcnt(" #n ")" ::: "memory")

// Wait-THEN-barrier (per-wave vmcnt drain of own tile-n loads, then make the
// whole tile globally visible). This is the only correct ordering for
// global_load_lds staging read by other waves.
#define BARRIER_KEEP4()  asm volatile("s_waitcnt vmcnt(4)\n\ts_barrier" ::: "memory")
#define BARRIER_KEEP0()  asm volatile("s_waitcnt vmcnt(0)\n\ts_barrier" ::: "memory")

// ---------------------------------------------------------------- fused convert
__global__ __launch_bounds__(256) void convert_all(const f32x4* __restrict__ h,
                                                   const f32x4* __restrict__ qw,
                                                   const f32x4* __restrict__ kw,
                                                   const f32x4* __restrict__ vw,
                                                   const f32x4* __restrict__ ow,
                                                   us4* __restrict__ hb,
                                                   us4* __restrict__ wqkv,
                                                   us4* __restrict__ owb) {
    const int N0 = 2097152;              // hidden  (2*2048*2048 /4)
    const int N1 = 1048576;              // q_w     (2048*2048 /4)
    const int N2 = 524288;               // k_w
    const int N3 = 524288;               // v_w
    int i = blockIdx.x * 256 + threadIdx.x;
    const f32x4* src; us4* dst;
    if (i < N0)                               { src = h  + i;                 dst = hb + i; }
    else if ((i -= N0) < N1)                  { src = qw + i;                 dst = wqkv + i; }
    else if ((i -= N1) < N2)                  { src = kw + i;                 dst = wqkv + 1048576 + i; }
    else if ((i -= N2) < N3)                  { src = vw + i;                 dst = wqkv + 1572864 + i; }
    else                                      { i -= N3; src = ow + i;       dst = owb + i; }
    f32x4 f = *src;
    us4 o;
    o[0] = f2bf(f[0]); o[1] = f2bf(f[1]); o[2] = f2bf(f[2]); o[3] = f2bf(f[3]);
    *dst = o;
}

// ---------------------------------------------------------------- GEMM C = A @ W^T
// 256x256 tile, BK=64, 8 waves (2x4), 8-phase schedule (T2+T3+T4+T5).
// (unchanged — verified in round 1)
template <typename OutT>
__global__ __launch_bounds__(512, 2) void gemm256(const ushort_t* __restrict__ A,
                                                  const ushort_t* __restrict__ W,
                                                  OutT* __restrict__ C,
                                                  int N, int K) {
    __shared__ ushort_t As[2][256 * 64];
    __shared__ ushort_t Bs[2][256 * 64];
    const int t = threadIdx.x;
    const int lane = t & 63;
    const int quad = lane >> 4, l16 = lane & 15;
    const int wm = t >> 8, wn = (t >> 6) & 3;        // 2 x 4 wave grid

    int bid = blockIdx.x;
    int xcd = bid & 7, j = bid >> 3;
    int tm, tn;
    if (N == 4096) { tm = (xcd >> 1) * 4 + (j >> 3); tn = (xcd & 1) * 8 + (j & 7); }
    else           { tm = xcd * 2 + (j >> 3);        tn = j & 7; }
    const int bm = tm * 256, bn = tn * 256;

    const int srow0 = t >> 3;                        // rows 0..63
    const int sg0 = ((t & 7) ^ (srow0 & 7)) * 8;     // inverse-swizzled src col
    const int srow1 = srow0 + 64;                    // rows 64..127
    const int sg1 = ((t & 7) ^ (srow1 & 7)) * 8;

    auto stageA = [&](int buf, int half, int k0) {
        gload_lds16(A + (size_t)(bm + half * 128 + srow0) * K + k0 + sg0,
                    &As[buf][half * 8192 + t * 8]);
        gload_lds16(A + (size_t)(bm + half * 128 + srow1) * K + k0 + sg1,
                    &As[buf][half * 8192 + 4096 + t * 8]);
    };
    auto stageB = [&](int buf, int half, int k0) {
        gload_lds16(W + (size_t)(bn + half * 128 + srow0) * K + k0 + sg0,
                    &Bs[buf][half * 8192 + t * 8]);
        gload_lds16(W + (size_t)(bn + half * 128 + srow1) * K + k0 + sg1,
                    &Bs[buf][half * 8192 + 4096 + t * 8]);
    };

    const int xsw = l16 & 7;
    const int arow = (wm * 128 + l16) * 64;
    const int brow = (wn * 64 + l16) * 64;
    const int ac0 = ((0 + quad) ^ xsw) * 8;          // kk=0 granule offset
    const int ac1 = ((4 + quad) ^ xsw) * 8;          // kk=1

    auto ldA = [&](int buf, int mf, int kk) {
        return ld_frag(&As[buf][arow + mf * 1024 + (kk ? ac1 : ac0)]);
    };
    auto ldB = [&](int buf, int nf, int kk) {
        return ld_frag(&Bs[buf][brow + nf * 1024 + (kk ? ac1 : ac0)]);
    };

    f32x4 acc[8][4];
#pragma unroll
    for (int i = 0; i < 8; i++)
#pragma unroll
        for (int jj = 0; jj < 4; jj++) acc[i][jj] = f32x4{0.f, 0.f, 0.f, 0.f};

    const int NIT = K >> 6;
    stageA(0, 0, 0); stageA(0, 1, 0); stageB(0, 0, 0); stageB(0, 1, 0);
    VMCNT(4);
    stageB(1, 0, 64); stageB(1, 1, 64); stageA(1, 0, 64);
    VMCNT(6);
    BAR();

    bf16x8 a[4][2], b[4][2];
    for (int tt = 0; tt < NIT; ++tt) {
        const int buf = tt & 1;
        const int k2 = (tt + 2) << 6;

        // ---- phase 1: quadrant (m-lo, n-lo). Read A-lo (8) + all B (8).
#pragma unroll
        for (int mt = 0; mt < 4; mt++) { a[mt][0] = ldA(buf, mt, 0); a[mt][1] = ldA(buf, mt, 1); }
#pragma unroll
        for (int nt = 0; nt < 4; nt++) { b[nt][0] = ldB(buf, nt, 0); b[nt][1] = ldB(buf, nt, 1); }
        if (tt + 1 < NIT) stageA(buf ^ 1, 1, (tt + 1) << 6);
        BAR(); LGKM0();
        __builtin_amdgcn_s_setprio(1);
#pragma unroll
        for (int mt = 0; mt < 4; mt++)
#pragma unroll
            for (int nt = 0; nt < 2; nt++)
#pragma unroll
                for (int kk = 0; kk < 2; kk++)
                    acc[mt][nt] = __builtin_amdgcn_mfma_f32_16x16x32_bf16(a[mt][kk], b[nt][kk], acc[mt][nt], 0, 0, 0);
        __builtin_amdgcn_s_setprio(0);
        LGKM0();
        BAR();

        // ---- phase 2: (m-lo, n-hi). B0 region fully consumed in P1.
        if (tt + 2 < NIT) stageB(buf, 0, k2);
        BAR();
        __builtin_amdgcn_s_setprio(1);
#pragma unroll
        for (int mt = 0; mt < 4; mt++)
#pragma unroll
            for (int nt = 0; nt < 2; nt++)
#pragma unroll
                for (int kk = 0; kk < 2; kk++)
                    acc[mt][2 + nt] = __builtin_amdgcn_mfma_f32_16x16x32_bf16(a[mt][kk], b[2 + nt][kk], acc[mt][2 + nt], 0, 0, 0);
        __builtin_amdgcn_s_setprio(0);
        BAR();

        // ---- phase 3: (m-hi, n-lo). Read A-hi (8).
#pragma unroll
        for (int mt = 0; mt < 4; mt++) { a[mt][0] = ldA(buf, 4 + mt, 0); a[mt][1] = ldA(buf, 4 + mt, 1); }
        if (tt + 2 < NIT) stageB(buf, 1, k2);
        BAR(); LGKM0();
        __builtin_amdgcn_s_setprio(1);
#pragma unroll
        for (int mt = 0; mt < 4; mt++)
#pragma unroll
            for (int nt = 0; nt < 2; nt++)
#pragma unroll
                for (int kk = 0; kk < 2; kk++)
                    acc[4 + mt][nt] = __builtin_amdgcn_mfma_f32_16x16x32_bf16(a[mt][kk], b[nt][kk], acc[4 + mt][nt], 0, 0, 0);
        __builtin_amdgcn_s_setprio(0);
        BAR();

        // ---- phase 4: (m-hi, n-hi). A0 region consumed by end of P3.
        if (tt + 2 < NIT)      { stageA(buf, 0, k2); VMCNT(6); }
        else if (tt + 1 < NIT) { VMCNT(0); }
        BAR();
        __builtin_amdgcn_s_setprio(1);
#pragma unroll
        for (int mt = 0; mt < 4; mt++)
#pragma unroll
            for (int nt = 0; nt < 2; nt++)
#pragma unroll
                for (int kk = 0; kk < 2; kk++)
                    acc[4 + mt][2 + nt] = __builtin_amdgcn_mfma_f32_16x16x32_bf16(a[mt][kk], b[2 + nt][kk], acc[4 + mt][2 + nt], 0, 0, 0);
        __builtin_amdgcn_s_setprio(0);
        BAR();
    }

#pragma unroll
    for (int mf = 0; mf < 8; mf++)
#pragma unroll
        for (int nf = 0; nf < 4; nf++) {
            const int row = bm + wm * 128 + mf * 16 + quad * 4;
            const int col = bn + wn * 64 + nf * 16 + l16;
#pragma unroll
            for (int rr = 0; rr < 4; rr++) {
                float v = acc[mf][nf][rr];
                if constexpr (sizeof(OutT) == 2)
                    C[(size_t)(row + rr) * N + col] = (OutT)f2bf(v);
                else
                    C[(size_t)(row + rr) * N + col] = v;
            }
        }
}

// ---------------------------------------------------------------- RoPE + l2norm
__global__ __launch_bounds__(256) void rope_norm(const ushort_t* __restrict__ qkv,
                                                 const float* __restrict__ cosb,
                                                 const float* __restrict__ sinb,
                                                 ushort_t* __restrict__ q,
                                                 ushort_t* __restrict__ k) {
    int row = blockIdx.x;                 // b*2048 + s
    int b = row >> 11, s = row & 2047;
    int w = threadIdx.x >> 6, lane = threadIdx.x & 63;
    int hh = blockIdx.y * 4 + w;          // 0..23
    const ushort_t* src = qkv + (size_t)row * 4096 + hh * 128;
    float x1 = bf2f(src[lane]);
    float x2 = bf2f(src[lane + 64]);
    float c = cosb[(size_t)row * 128 + lane];
    float sn = sinb[(size_t)row * 128 + lane];
    float y1 = x1 * c + x2 * sn;
    float y2 = x2 * c - x1 * sn;
    float ss = y1 * y1 + y2 * y2;
#pragma unroll
    for (int off = 1; off < 64; off <<= 1) ss += __shfl_xor(ss, off);
    float rinv = rsqrtf(ss * (1.0f / 128.0f) + 1e-6f);
    y1 *= rinv; y2 *= rinv;
    ushort_t* dst;
    if (hh < 16) dst = q + (((size_t)(b * 16 + hh)) * 2048 + s) * 128;
    else         dst = k + (((size_t)(b * 8 + hh - 16)) * 2048 + s) * 128;
    dst[lane] = f2bf(y1);
    dst[lane + 64] = f2bf(y2);
}

// ---------------------------------------------------------------- V transpose
__global__ __launch_bounds__(256) void v_transpose(const ushort_t* __restrict__ qkv,
                                                   ushort_t* __restrict__ vt) {
    __shared__ ushort_t tile[64 * 72];
    int t = threadIdx.x;
    int s0 = blockIdx.x * 64, d0 = blockIdx.y * 64, bh = blockIdx.z;
    int b = bh >> 3, kvh = bh & 7;
    {
        int sl = t >> 2, c = t & 3;
        const ushort_t* src = qkv + (size_t)(b * 2048 + s0 + sl) * 4096 + 3072 + kvh * 128 + d0 + c * 16;
        u32x4 v0 = *(const u32x4*)src;
        u32x4 v1 = *(const u32x4*)(src + 8);
        *(u32x4*)&tile[sl * 72 + c * 16] = v0;
        *(u32x4*)&tile[sl * 72 + c * 16 + 8] = v1;
    }
    __syncthreads();
    {
        int dl = t >> 2, c = t & 3;
        alignas(16) ushort_t tmp[16];
#pragma unroll
        for (int i = 0; i < 16; i++) tmp[i] = tile[(c * 16 + i) * 72 + dl];
        ushort_t* dst = vt + (size_t)(bh * 128 + d0 + dl) * 2048 + s0 + c * 16;
        *(u32x4*)dst = *(const u32x4*)&tmp[0];
        *(u32x4*)(dst + 8) = *(const u32x4*)&tmp[8];
    }
}

// ---------------------------------------------------------------- Flash attention
// v3: 512 threads = 8 waves (2/SIMD). Wave (w4, wh): w4 = 16-q-row chunk (both
// heads), wh = kv-col-half for QK^T / d-half for PV. P shared via LDS with a
// cross-wave barrier. Staging uses the VERIFIED v1 skeleton: triple-buffered
// K/V, distance-2 prefetch, wait-THEN-barrier (BARRIER_KEEP4: drain own tile-n
// loads, keep tile n+1's 4 in flight). LDS: 96KB K/V + 18KB P -> 1 block/CU.
__global__ __launch_bounds__(512) void flash_attn(const ushort_t* __restrict__ q,
                                                  const ushort_t* __restrict__ k,
                                                  const ushort_t* __restrict__ vt,
                                                  ushort_t* __restrict__ attn) {
    __shared__ ushort_t Ks[3][4 * 64 * 32];      // 3 x 16 KB  [qd][64][32]
    __shared__ ushort_t Vts[3][2 * 128 * 32];    // 3 x 16 KB  [ks][128][32]
    __shared__ ushort_t Ps[2 * 64 * 72];         // 18 KB      [h][row][72]
    __shared__ float    Lred[2][4][2][16];       // [wh][w4][h][row16]
    const int t = threadIdx.x;
    const int w = t >> 6, lane = t & 63;
    const int w4 = w & 3, wh = w >> 2;
    const int quad = lane >> 4, l16 = lane & 15;
    const int sw = (l16 >> 1) & 3;
    const int lid = blockIdx.x;
    const int xcd = lid & 7, jj = lid >> 3;
    const int g = xcd * 2 + (jj >> 4);           // (b,kvh) group, 2 per XCD
    const int p = jj & 15;                       // q-tile pair index 0..15
    const int b = g >> 3, kvh = g & 7;
    const int h0 = kvh * 2;
    const size_t kbase = ((size_t)(b * 8 + kvh)) * 2048 * 128;
    const size_t vbase = ((size_t)(b * 8 + kvh)) * 128 * 2048;

    const float C1 = 0.12751744f;   // (1/sqrt(128)) * log2(e)
    const float C2 = 1.45f;         // fixed max in log2 domain

    auto stage = [&](int j0, int buf) {
#pragma unroll
        for (int i = 0; i < 2; i++) {            // K tile (16KB), k-blocked
            int u = i * 512 + t;
            int qd = u >> 8, rr = (u >> 2) & 63;
            int c4 = ((u & 3) ^ ((rr >> 1) & 3)) * 8;
            gload_lds16(k + kbase + (size_t)(j0 + rr) * 128 + qd * 32 + c4,
                        (char*)Ks[buf] + u * 16);
        }
#pragma unroll
        for (int i = 0; i < 2; i++) {            // Vt tile (16KB), k-blocked
            int u = i * 512 + t;
            int ks = u >> 9, dd = (u >> 2) & 127;
            int c4 = ((u & 3) ^ ((dd >> 1) & 3)) * 8;
            gload_lds16(vt + vbase + (size_t)dd * 2048 + j0 + ks * 32 + c4,
                        (char*)Vts[buf] + u * 16);
        }
    };

    const int qtile0 = 31 - p;                   // heavy pass first
    const int S_total = qtile0 + 1 + p + 1;      // tile-stream length (=33)
    auto j0_of = [&](int s) { return (s <= qtile0 ? s : s - qtile0 - 1) * 64; };

    stage(j0_of(0), 0);
    stage(j0_of(1), 1);
    int sidx = 0, cb = 0, pb = 2;

    for (int pass = 0; pass < 2; ++pass) {
        const int qi = pass ? p : qtile0;
        const int q0 = qi * 64;

        bf16x8 qf[2][4];
#pragma unroll
        for (int h = 0; h < 2; h++) {
            const size_t qbase = ((size_t)(b * 16 + h0 + h) * 2048 + q0 + w4 * 16 + l16) * 128;
#pragma unroll
            for (int qd = 0; qd < 4; qd++) {
                us8 v = *(const us8*)(q + qbase + qd * 32 + quad * 8);
                qf[h][qd] = __builtin_bit_cast(bf16x8, v);
            }
        }

        f32x4 o[2][4];
#pragma unroll
        for (int h = 0; h < 2; h++)
#pragma unroll
            for (int i = 0; i < 4; i++) o[h][i] = f32x4{0.f, 0.f, 0.f, 0.f};
        float lsum[2][4];
#pragma unroll
        for (int h = 0; h < 2; h++)
#pragma unroll
            for (int r = 0; r < 4; r++) lsum[h][r] = 0.f;

        for (int jt = 0; jt <= qi; ++jt) {
            const int j0 = jt * 64;
            const bool diag = (jt == qi);
            // drain own tile-sidx loads, keep tile sidx+1's in flight; barrier
            // makes the whole tile visible to all waves.
            if (sidx + 1 < S_total) BARRIER_KEEP4();
            else                    BARRIER_KEEP0();
            if (sidx + 2 < S_total) stage(j0_of(sidx + 2), pb);
            const ushort_t* Kb = Ks[cb];
            const ushort_t* Vb = Vts[cb];
            cb = cb == 2 ? 0 : cb + 1;
            pb = pb == 2 ? 0 : pb + 1;
            sidx++;

            // S = Q K^T, this wave's 32-kv-col half, both heads
            f32x4 sc[2][2];
#pragma unroll
            for (int h = 0; h < 2; h++)
#pragma unroll
                for (int c = 0; c < 2; c++) sc[h][c] = f32x4{0.f, 0.f, 0.f, 0.f};
            __builtin_amdgcn_s_setprio(1);
#pragma unroll
            for (int c = 0; c < 2; c++)
#pragma unroll
                for (int qd = 0; qd < 4; qd++) {
                    bf16x8 kf = ld_frag(&Kb[qd * 2048 + ((wh * 2 + c) * 16 + l16) * 32 + (quad ^ sw) * 8]);
                    sc[0][c] = __builtin_amdgcn_mfma_f32_16x16x32_bf16(qf[0][qd], kf, sc[0][c], 0, 0, 0);
                    sc[1][c] = __builtin_amdgcn_mfma_f32_16x16x32_bf16(qf[1][qd], kf, sc[1][c], 0, 0, 0);
                }
            __builtin_amdgcn_s_setprio(0);

            // p = exp2(s*C1 - C2); mask only on the diagonal tile
#pragma unroll
            for (int c = 0; c < 2; c++)
#pragma unroll
                for (int r = 0; r < 4; r++) {
                    float p0 = __builtin_amdgcn_exp2f(sc[0][c][r] * C1 - C2);
                    float p1 = __builtin_amdgcn_exp2f(sc[1][c][r] * C1 - C2);
                    if (diag) {
                        int kg = j0 + wh * 32 + c * 16 + l16;
                        int qg = q0 + w4 * 16 + quad * 4 + r;
                        if (kg > qg) { p0 = 0.f; p1 = 0.f; }
                    }
                    lsum[0][r] += p0;
                    lsum[1][r] += p1;
                    int prow = w4 * 16 + quad * 4 + r;
                    int pcol = wh * 32 + c * 16 + l16;
                    Ps[prow * 72 + pcol] = f2bf(p0);
                    Ps[4608 + prow * 72 + pcol] = f2bf(p1);
                }
            LGKM0();
            BAR();                               // full P tile visible

            // O += P V, this wave's 64-d half, both heads
            __builtin_amdgcn_s_setprio(1);
#pragma unroll
            for (int ks = 0; ks < 2; ks++) {
                bf16x8 pf0 = ld_frag(&Ps[(w4 * 16 + l16) * 72 + ks * 32 + quad * 8]);
                bf16x8 pf1 = ld_frag(&Ps[4608 + (w4 * 16 + l16) * 72 + ks * 32 + quad * 8]);
#pragma unroll
                for (int od = 0; od < 4; od++) {
                    bf16x8 vf = ld_frag(&Vb[ks * 4096 + (wh * 64 + od * 16 + l16) * 32 + (quad ^ sw) * 8]);
                    o[0][od] = __builtin_amdgcn_mfma_f32_16x16x32_bf16(pf0, vf, o[0][od], 0, 0, 0);
                    o[1][od] = __builtin_amdgcn_mfma_f32_16x16x32_bf16(pf1, vf, o[1][od], 0, 0, 0);
                }
            }
            __builtin_amdgcn_s_setprio(0);
        }

        // epilogue: cross-wave lsum reduce, then store this wave's d-half
        float rl[2][4];
#pragma unroll
        for (int h = 0; h < 2; h++)
#pragma unroll
            for (int r = 0; r < 4; r++) {
                float s = lsum[h][r];
#pragma unroll
                for (int off = 1; off < 16; off <<= 1) s += __shfl_xor(s, off);
                if (l16 == 0) Lred[wh][w4][h][quad * 4 + r] = s;
            }
        LGKM0();
        BAR();
#pragma unroll
        for (int h = 0; h < 2; h++)
#pragma unroll
            for (int r = 0; r < 4; r++)
                rl[h][r] = 1.0f / (Lred[0][w4][h][quad * 4 + r] + Lred[1][w4][h][quad * 4 + r]);

#pragma unroll
        for (int h = 0; h < 2; h++) {
            const size_t obase = ((size_t)(b * 2048 + q0 + w4 * 16 + quad * 4)) * 2048
                                 + (h0 + h) * 128 + wh * 64;
#pragma unroll
            for (int od = 0; od < 4; od++)
#pragma unroll
                for (int r = 0; r < 4; r++)
                    attn[obase + (size_t)r * 2048 + od * 16 + l16] = f2bf(o[h][od][r] * rl[h][r]);
        }
    }
}

// ---------------------------------------------------------------- launch
extern "C" void kernel_launch(void* const* d_in, const int* in_sizes, int n_in,
                              void* d_out, int out_size, void* d_ws, size_t ws_size,
                              hipStream_t stream) {
    (void)in_sizes; (void)n_in; (void)out_size; (void)ws_size;
    const float* hidden = (const float*)d_in[0];
    const float* cosb   = (const float*)d_in[1];
    const float* sinb   = (const float*)d_in[2];
    // d_in[3] = attention_mask: causal, computed inline
    const float* q_w    = (const float*)d_in[4];
    const float* k_w    = (const float*)d_in[5];
    const float* v_w    = (const float*)d_in[6];
    const float* o_w    = (const float*)d_in[7];

    char* ws = (char*)d_ws;                                  // 104 MB used
    ushort_t* hb   = (ushort_t*)(ws);                        // [4096][2048] bf16 hidden
    ushort_t* wqkv = (ushort_t*)(ws + (16ull << 20));        // [4096][2048] bf16 q|k|v weights
    ushort_t* owb  = (ushort_t*)(ws + (32ull << 20));        // [2048][2048] bf16 o_w
    ushort_t* qkv  = (ushort_t*)(ws + (40ull << 20));        // [4096][4096] bf16 qkv proj
    ushort_t* attn = qkv;                                    // alias: qkv consumed before flash
    ushort_t* qb   = (ushort_t*)(ws + (72ull << 20));        // [2][16][2048][128]
    ushort_t* kb   = (ushort_t*)(ws + (88ull << 20));        // [2][8][2048][128]
    ushort_t* vt   = (ushort_t*)(ws + (96ull << 20));        // [2][8][128][2048]

    convert_all<<<20480, 256, 0, stream>>>((const f32x4*)hidden, (const f32x4*)q_w,
                                           (const f32x4*)k_w, (const f32x4*)v_w,
                                           (const f32x4*)o_w,
                                           (us4*)hb, (us4*)wqkv, (us4*)owb);

    gemm256<ushort_t><<<256, 512, 0, stream>>>(hb, wqkv, qkv, 4096, 2048);
    rope_norm<<<dim3(4096, 6), 256, 0, stream>>>(qkv, cosb, sinb, qb, kb);
    v_transpose<<<dim3(32, 2, 16), 256, 0, stream>>>(qkv, vt);
    flash_attn<<<256, 512, 0, stream>>>(qb, kb, vt, attn);
    gemm256<float><<<128, 512, 0, stream>>>(attn, owb, (float*)d_out, 2048, 2048);
}

// Round 4
// 336.271 us; speedup vs baseline: 1.1084x; 1.0401x over previous
//
#include <hip/hip_runtime.h>

typedef unsigned short ushort_t;
typedef __bf16 bf16x8 __attribute__((ext_vector_type(8)));
typedef float f32x4 __attribute__((ext_vector_type(4)));
typedef float f32x16 __attribute__((ext_vector_type(16)));
typedef unsigned int u32x4 __attribute__((ext_vector_type(4)));
typedef unsigned short us4 __attribute__((ext_vector_type(4)));
typedef unsigned short us8 __attribute__((ext_vector_type(8)));

#define DEVINL __device__ __forceinline__

DEVINL ushort_t f2bf(float f) {
    unsigned u = __float_as_uint(f);
    u += 0x7FFF + ((u >> 16) & 1);   // RNE
    return (ushort_t)(u >> 16);
}
DEVINL float bf2f(ushort_t h) { return __uint_as_float(((unsigned)h) << 16); }

DEVINL void gload_lds16(const void* g, void* l) {
    __builtin_amdgcn_global_load_lds(
        (const __attribute__((address_space(1))) void*)g,
        (__attribute__((address_space(3))) void*)l, 16, 0, 0);
}

DEVINL bf16x8 ld_frag(const ushort_t* p) {
    us8 v = *(const us8*)p;
    return __builtin_bit_cast(bf16x8, v);
}

// pack 2 f32 -> u32 of 2 bf16 (lo = a, hi = b), RNE
DEVINL unsigned cvt_pk_bf16(float a, float b) {
    unsigned r;
    asm("v_cvt_pk_bf16_f32 %0, %1, %2" : "=v"(r) : "v"(a), "v"(b));
    return r;
}
// swap a's upper 32 lanes with b's lower 32 lanes (both modified)
#define PERMSWAP(a, b) asm volatile("v_permlane32_swap_b32 %0, %1" : "+v"(a), "+v"(b))

#define BAR()     asm volatile("s_barrier" ::: "memory")
#define LGKM0()   asm volatile("s_waitcnt lgkmcnt(0)" ::: "memory")
#define VMCNT(n)  asm volatile("s_waitcnt vmcnt(" #n ")" ::: "memory")
// Wait-THEN-barrier: drain own staging loads, then make tile globally visible.
#define BARRIER_DRAIN() asm volatile("s_waitcnt vmcnt(0)\n\ts_barrier" ::: "memory")

// ---------------------------------------------------------------- fused convert
__global__ __launch_bounds__(256) void convert_all(const f32x4* __restrict__ h,
                                                   const f32x4* __restrict__ qw,
                                                   const f32x4* __restrict__ kw,
                                                   const f32x4* __restrict__ vw,
                                                   const f32x4* __restrict__ ow,
                                                   us4* __restrict__ hb,
                                                   us4* __restrict__ wqkv,
                                                   us4* __restrict__ owb) {
    const int N0 = 2097152;              // hidden  (2*2048*2048 /4)
    const int N1 = 1048576;              // q_w     (2048*2048 /4)
    const int N2 = 524288;               // k_w
    const int N3 = 524288;               // v_w
    int i = blockIdx.x * 256 + threadIdx.x;
    const f32x4* src; us4* dst;
    if (i < N0)                               { src = h  + i;                 dst = hb + i; }
    else if ((i -= N0) < N1)                  { src = qw + i;                 dst = wqkv + i; }
    else if ((i -= N1) < N2)                  { src = kw + i;                 dst = wqkv + 1048576 + i; }
    else if ((i -= N2) < N3)                  { src = vw + i;                 dst = wqkv + 1572864 + i; }
    else                                      { i -= N3; src = ow + i;       dst = owb + i; }
    f32x4 f = *src;
    us4 o;
    o[0] = f2bf(f[0]); o[1] = f2bf(f[1]); o[2] = f2bf(f[2]); o[3] = f2bf(f[3]);
    *dst = o;
}

// ---------------------------------------------------------------- GEMM C = A @ W^T
// 256x256 tile, BK=64, 8 waves (2x4), 8-phase schedule (T2+T3+T4+T5).
// (unchanged — verified)
template <typename OutT>
__global__ __launch_bounds__(512, 2) void gemm256(const ushort_t* __restrict__ A,
                                                  const ushort_t* __restrict__ W,
                                                  OutT* __restrict__ C,
                                                  int N, int K) {
    __shared__ ushort_t As[2][256 * 64];
    __shared__ ushort_t Bs[2][256 * 64];
    const int t = threadIdx.x;
    const int lane = t & 63;
    const int quad = lane >> 4, l16 = lane & 15;
    const int wm = t >> 8, wn = (t >> 6) & 3;        // 2 x 4 wave grid

    int bid = blockIdx.x;
    int xcd = bid & 7, j = bid >> 3;
    int tm, tn;
    if (N == 4096) { tm = (xcd >> 1) * 4 + (j >> 3); tn = (xcd & 1) * 8 + (j & 7); }
    else           { tm = xcd * 2 + (j >> 3);        tn = j & 7; }
    const int bm = tm * 256, bn = tn * 256;

    const int srow0 = t >> 3;                        // rows 0..63
    const int sg0 = ((t & 7) ^ (srow0 & 7)) * 8;     // inverse-swizzled src col
    const int srow1 = srow0 + 64;                    // rows 64..127
    const int sg1 = ((t & 7) ^ (srow1 & 7)) * 8;

    auto stageA = [&](int buf, int half, int k0) {
        gload_lds16(A + (size_t)(bm + half * 128 + srow0) * K + k0 + sg0,
                    &As[buf][half * 8192 + t * 8]);
        gload_lds16(A + (size_t)(bm + half * 128 + srow1) * K + k0 + sg1,
                    &As[buf][half * 8192 + 4096 + t * 8]);
    };
    auto stageB = [&](int buf, int half, int k0) {
        gload_lds16(W + (size_t)(bn + half * 128 + srow0) * K + k0 + sg0,
                    &Bs[buf][half * 8192 + t * 8]);
        gload_lds16(W + (size_t)(bn + half * 128 + srow1) * K + k0 + sg1,
                    &Bs[buf][half * 8192 + 4096 + t * 8]);
    };

    const int xsw = l16 & 7;
    const int arow = (wm * 128 + l16) * 64;
    const int brow = (wn * 64 + l16) * 64;
    const int ac0 = ((0 + quad) ^ xsw) * 8;          // kk=0 granule offset
    const int ac1 = ((4 + quad) ^ xsw) * 8;          // kk=1

    auto ldA = [&](int buf, int mf, int kk) {
        return ld_frag(&As[buf][arow + mf * 1024 + (kk ? ac1 : ac0)]);
    };
    auto ldB = [&](int buf, int nf, int kk) {
        return ld_frag(&Bs[buf][brow + nf * 1024 + (kk ? ac1 : ac0)]);
    };

    f32x4 acc[8][4];
#pragma unroll
    for (int i = 0; i < 8; i++)
#pragma unroll
        for (int jj = 0; jj < 4; jj++) acc[i][jj] = f32x4{0.f, 0.f, 0.f, 0.f};

    const int NIT = K >> 6;
    stageA(0, 0, 0); stageA(0, 1, 0); stageB(0, 0, 0); stageB(0, 1, 0);
    VMCNT(4);
    stageB(1, 0, 64); stageB(1, 1, 64); stageA(1, 0, 64);
    VMCNT(6);
    BAR();

    bf16x8 a[4][2], b[4][2];
    for (int tt = 0; tt < NIT; ++tt) {
        const int buf = tt & 1;
        const int k2 = (tt + 2) << 6;

        // ---- phase 1: quadrant (m-lo, n-lo). Read A-lo (8) + all B (8).
#pragma unroll
        for (int mt = 0; mt < 4; mt++) { a[mt][0] = ldA(buf, mt, 0); a[mt][1] = ldA(buf, mt, 1); }
#pragma unroll
        for (int nt = 0; nt < 4; nt++) { b[nt][0] = ldB(buf, nt, 0); b[nt][1] = ldB(buf, nt, 1); }
        if (tt + 1 < NIT) stageA(buf ^ 1, 1, (tt + 1) << 6);
        BAR(); LGKM0();
        __builtin_amdgcn_s_setprio(1);
#pragma unroll
        for (int mt = 0; mt < 4; mt++)
#pragma unroll
            for (int nt = 0; nt < 2; nt++)
#pragma unroll
                for (int kk = 0; kk < 2; kk++)
                    acc[mt][nt] = __builtin_amdgcn_mfma_f32_16x16x32_bf16(a[mt][kk], b[nt][kk], acc[mt][nt], 0, 0, 0);
        __builtin_amdgcn_s_setprio(0);
        LGKM0();
        BAR();

        // ---- phase 2: (m-lo, n-hi). B0 region fully consumed in P1.
        if (tt + 2 < NIT) stageB(buf, 0, k2);
        BAR();
        __builtin_amdgcn_s_setprio(1);
#pragma unroll
        for (int mt = 0; mt < 4; mt++)
#pragma unroll
            for (int nt = 0; nt < 2; nt++)
#pragma unroll
                for (int kk = 0; kk < 2; kk++)
                    acc[mt][2 + nt] = __builtin_amdgcn_mfma_f32_16x16x32_bf16(a[mt][kk], b[2 + nt][kk], acc[mt][2 + nt], 0, 0, 0);
        __builtin_amdgcn_s_setprio(0);
        BAR();

        // ---- phase 3: (m-hi, n-lo). Read A-hi (8).
#pragma unroll
        for (int mt = 0; mt < 4; mt++) { a[mt][0] = ldA(buf, 4 + mt, 0); a[mt][1] = ldA(buf, 4 + mt, 1); }
        if (tt + 2 < NIT) stageB(buf, 1, k2);
        BAR(); LGKM0();
        __builtin_amdgcn_s_setprio(1);
#pragma unroll
        for (int mt = 0; mt < 4; mt++)
#pragma unroll
            for (int nt = 0; nt < 2; nt++)
#pragma unroll
                for (int kk = 0; kk < 2; kk++)
                    acc[4 + mt][nt] = __builtin_amdgcn_mfma_f32_16x16x32_bf16(a[mt][kk], b[nt][kk], acc[4 + mt][nt], 0, 0, 0);
        __builtin_amdgcn_s_setprio(0);
        BAR();

        // ---- phase 4: (m-hi, n-hi). A0 region consumed by end of P3.
        if (tt + 2 < NIT)      { stageA(buf, 0, k2); VMCNT(6); }
        else if (tt + 1 < NIT) { VMCNT(0); }
        BAR();
        __builtin_amdgcn_s_setprio(1);
#pragma unroll
        for (int mt = 0; mt < 4; mt++)
#pragma unroll
            for (int nt = 0; nt < 2; nt++)
#pragma unroll
                for (int kk = 0; kk < 2; kk++)
                    acc[4 + mt][2 + nt] = __builtin_amdgcn_mfma_f32_16x16x32_bf16(a[mt][kk], b[2 + nt][kk], acc[4 + mt][2 + nt], 0, 0, 0);
        __builtin_amdgcn_s_setprio(0);
        BAR();
    }

#pragma unroll
    for (int mf = 0; mf < 8; mf++)
#pragma unroll
        for (int nf = 0; nf < 4; nf++) {
            const int row = bm + wm * 128 + mf * 16 + quad * 4;
            const int col = bn + wn * 64 + nf * 16 + l16;
#pragma unroll
            for (int rr = 0; rr < 4; rr++) {
                float v = acc[mf][nf][rr];
                if constexpr (sizeof(OutT) == 2)
                    C[(size_t)(row + rr) * N + col] = (OutT)f2bf(v);
                else
                    C[(size_t)(row + rr) * N + col] = v;
            }
        }
}

// ---------------------------------------------------------------- RoPE + l2norm
__global__ __launch_bounds__(256) void rope_norm(const ushort_t* __restrict__ qkv,
                                                 const float* __restrict__ cosb,
                                                 const float* __restrict__ sinb,
                                                 ushort_t* __restrict__ q,
                                                 ushort_t* __restrict__ k) {
    int row = blockIdx.x;                 // b*2048 + s
    int b = row >> 11, s = row & 2047;
    int w = threadIdx.x >> 6, lane = threadIdx.x & 63;
    int hh = blockIdx.y * 4 + w;          // 0..23
    const ushort_t* src = qkv + (size_t)row * 4096 + hh * 128;
    float x1 = bf2f(src[lane]);
    float x2 = bf2f(src[lane + 64]);
    float c = cosb[(size_t)row * 128 + lane];
    float sn = sinb[(size_t)row * 128 + lane];
    float y1 = x1 * c + x2 * sn;
    float y2 = x2 * c - x1 * sn;
    float ss = y1 * y1 + y2 * y2;
#pragma unroll
    for (int off = 1; off < 64; off <<= 1) ss += __shfl_xor(ss, off);
    float rinv = rsqrtf(ss * (1.0f / 128.0f) + 1e-6f);
    y1 *= rinv; y2 *= rinv;
    ushort_t* dst;
    if (hh < 16) dst = q + (((size_t)(b * 16 + hh)) * 2048 + s) * 128;
    else         dst = k + (((size_t)(b * 8 + hh - 16)) * 2048 + s) * 128;
    dst[lane] = f2bf(y1);
    dst[lane + 64] = f2bf(y2);
}

// ---------------------------------------------------------------- V transpose
__global__ __launch_bounds__(256) void v_transpose(const ushort_t* __restrict__ qkv,
                                                   ushort_t* __restrict__ vt) {
    __shared__ ushort_t tile[64 * 72];
    int t = threadIdx.x;
    int s0 = blockIdx.x * 64, d0 = blockIdx.y * 64, bh = blockIdx.z;
    int b = bh >> 3, kvh = bh & 7;
    {
        int sl = t >> 2, c = t & 3;
        const ushort_t* src = qkv + (size_t)(b * 2048 + s0 + sl) * 4096 + 3072 + kvh * 128 + d0 + c * 16;
        u32x4 v0 = *(const u32x4*)src;
        u32x4 v1 = *(const u32x4*)(src + 8);
        *(u32x4*)&tile[sl * 72 + c * 16] = v0;
        *(u32x4*)&tile[sl * 72 + c * 16 + 8] = v1;
    }
    __syncthreads();
    {
        int dl = t >> 2, c = t & 3;
        alignas(16) ushort_t tmp[16];
#pragma unroll
        for (int i = 0; i < 16; i++) tmp[i] = tile[(c * 16 + i) * 72 + dl];
        ushort_t* dst = vt + (size_t)(bh * 128 + d0 + dl) * 2048 + s0 + c * 16;
        *(u32x4*)dst = *(const u32x4*)&tmp[0];
        *(u32x4*)(dst + 8) = *(const u32x4*)&tmp[8];
    }
}

// ---------------------------------------------------------------- Flash attention
// v4: 32x32 MFMA, swapped QK^T (mfma(K,Q)) -> P lane-local; cvt_pk +
// permlane32_swap builds the PV A-frag fully in registers. No P LDS, ONE
// barrier per iteration. 8 waves (512 thr): wave = (wk kv-half, chunk q-32,
// wh head). Partial O over kv-halves merged once per pass via 64KB LDS.
// K/V double-buffered, distance-1 prefetch, wait-then-barrier discipline.
__global__ __launch_bounds__(512, 2) void flash_attn(const ushort_t* __restrict__ q,
                                                     const ushort_t* __restrict__ k,
                                                     const ushort_t* __restrict__ vt,
                                                     ushort_t* __restrict__ attn) {
    __shared__ ushort_t Ks[2][4 * 64 * 32];      // 2 x 16 KB  [qd][64 kv][32]
    __shared__ ushort_t Vts[2][2 * 128 * 32];    // 2 x 16 KB  [ks][128 d][32 kv]
    __shared__ float    Om[4][16][64][4];        // 64 KB o-merge scratch
    __shared__ float    Ls[2][4][32];            // lsum partials [wk][pid][qrow]
    const int t = threadIdx.x;
    const int w = t >> 6, lane = t & 63;
    const int wh = w & 1, chunk = (w >> 1) & 1, wk = w >> 2;
    const int pid = chunk * 2 + wh;
    const int l31 = lane & 31, hi = lane >> 5;
    const int swz = (l31 >> 1) & 3;
    const int lid = blockIdx.x;
    const int xcd = lid & 7, jj = lid >> 3;
    const int g = xcd * 2 + (jj >> 4);           // (b,kvh) group, 2 per XCD
    const int p = jj & 15;                       // q-tile pair index 0..15
    const int b = g >> 3, kvh = g & 7;
    const int h0 = kvh * 2;
    const size_t kbase = ((size_t)(b * 8 + kvh)) * 2048 * 128;
    const size_t vbase = ((size_t)(b * 8 + kvh)) * 128 * 2048;

    const float C1 = 0.12751744f;   // (1/sqrt(128)) * log2(e)
    const float C2 = 1.45f;         // fixed max in log2 domain

    auto stage = [&](int j0, int buf) {
#pragma unroll
        for (int i = 0; i < 2; i++) {            // K tile (16KB)
            int u = i * 512 + t;
            int qd = u >> 8, rr = (u >> 2) & 63;
            int c4 = ((u & 3) ^ ((rr >> 1) & 3)) * 8;
            gload_lds16(k + kbase + (size_t)(j0 + rr) * 128 + qd * 32 + c4,
                        (char*)Ks[buf] + u * 16);
        }
#pragma unroll
        for (int i = 0; i < 2; i++) {            // Vt tile (16KB)
            int u = i * 512 + t;
            int ks = u >> 9, dd = (u >> 2) & 127;
            int c4 = ((u & 3) ^ ((dd >> 1) & 3)) * 8;
            gload_lds16(vt + vbase + (size_t)dd * 2048 + j0 + ks * 32 + c4,
                        (char*)Vts[buf] + u * 16);
        }
    };

    const int qtile0 = 31 - p;                   // heavy pass first
    const int S_total = qtile0 + 1 + p + 1;      // tile-stream length (=33)
    auto j0_of = [&](int s) { return (s <= qtile0 ? s : s - qtile0 - 1) * 64; };

    stage(j0_of(0), 0);
    int sidx = 0;

    for (int pass = 0; pass < 2; ++pass) {
        const int qi = pass ? p : qtile0;
        const int q0 = qi * 64;
        const int hgl = h0 + wh;
        const int qg = q0 + chunk * 32 + l31;    // this lane's q-row (B side)

        // Q B-frags from global: lane row = q (l31), k = s*16 + hi*8
        bf16x8 qf[8];
        {
            const size_t qrow = ((size_t)(b * 16 + hgl) * 2048 + qg) * 128;
#pragma unroll
            for (int s = 0; s < 8; s++) {
                us8 v = *(const us8*)(q + qrow + s * 16 + hi * 8);
                qf[s] = __builtin_bit_cast(bf16x8, v);
            }
        }

        f32x16 o[4];
#pragma unroll
        for (int i = 0; i < 4; i++)
#pragma unroll
            for (int r = 0; r < 16; r++) o[i][r] = 0.f;
        float lsum = 0.f;

        for (int jt = 0; jt <= qi; ++jt) {
            const int j0 = jt * 64;
            const bool diag = (jt == qi);
            const int buf = sidx & 1;
            BARRIER_DRAIN();                     // drain own tile-sidx loads; tile visible
            if (sidx + 1 < S_total) stage(j0_of(sidx + 1), buf ^ 1);
            sidx++;

            // ---- QK^T swapped: sc = K(32kv) x Q(32q), k-dim = d = 128
            f32x16 sc;
#pragma unroll
            for (int r = 0; r < 16; r++) sc[r] = 0.f;
            __builtin_amdgcn_s_setprio(1);
#pragma unroll
            for (int s = 0; s < 8; s++) {
                bf16x8 kf = ld_frag(&Ks[buf][(s >> 1) * 2048 + (wk * 32 + l31) * 32 +
                                             (((((s & 1) << 1) | hi)) ^ swz) * 8]);
                sc = __builtin_amdgcn_mfma_f32_32x32x16_bf16(kf, qf[s], sc, 0, 0, 0);
            }
            __builtin_amdgcn_s_setprio(0);

            // ---- softmax in-register: lane holds 16 kv values for q-row l31
#pragma unroll
            for (int r = 0; r < 16; r++)
                sc[r] = __builtin_amdgcn_exp2f(sc[r] * C1 - C2);
            if (diag) {
                const int kvb = j0 + wk * 32 + 4 * hi;
#pragma unroll
                for (int r = 0; r < 16; r++) {
                    int kg = kvb + (r & 3) + 8 * (r >> 2);
                    if (kg > qg) sc[r] = 0.f;
                }
            }
#pragma unroll
            for (int r = 0; r < 16; r++) lsum += sc[r];

            // ---- pack P -> PV A-frags (2 k-steps of 16) via cvt_pk + permlane
            bf16x8 pf[2];
#pragma unroll
            for (int kp = 0; kp < 2; kp++) {
                const int rb = kp * 8;
                unsigned x0 = cvt_pk_bf16(sc[rb + 0], sc[rb + 1]);
                unsigned x1 = cvt_pk_bf16(sc[rb + 2], sc[rb + 3]);
                unsigned y0 = cvt_pk_bf16(sc[rb + 4], sc[rb + 5]);
                unsigned y1 = cvt_pk_bf16(sc[rb + 6], sc[rb + 7]);
                PERMSWAP(x0, y0);
                PERMSWAP(x1, y1);
                u32x4 pv; pv[0] = x0; pv[1] = x1; pv[2] = y0; pv[3] = y1;
                pf[kp] = __builtin_bit_cast(bf16x8, pv);
            }

            // ---- PV: o(32q x 32d per od) += P(32q x 32kv) x V^T(32d x 32kv)
            __builtin_amdgcn_s_setprio(1);
#pragma unroll
            for (int kp = 0; kp < 2; kp++)
#pragma unroll
                for (int od = 0; od < 4; od++) {
                    bf16x8 vf = ld_frag(&Vts[buf][wk * 4096 + (od * 32 + l31) * 32 +
                                                  ((((kp << 1) | hi)) ^ swz) * 8]);
                    o[od] = __builtin_amdgcn_mfma_f32_32x32x16_bf16(pf[kp], vf, o[od], 0, 0, 0);
                }
            __builtin_amdgcn_s_setprio(0);
        }

        // ---- pass epilogue: merge kv-halves, normalize, store
        lsum += __shfl_xor(lsum, 32);
        if (hi == 0) Ls[wk][pid][l31] = lsum;
        if (wk == 1) {
#pragma unroll
            for (int od = 0; od < 4; od++)
#pragma unroll
                for (int r4 = 0; r4 < 4; r4++) {
                    f32x4 v;
                    v[0] = o[od][r4 * 4 + 0]; v[1] = o[od][r4 * 4 + 1];
                    v[2] = o[od][r4 * 4 + 2]; v[3] = o[od][r4 * 4 + 3];
                    *(f32x4*)&Om[pid][od * 4 + r4][lane][0] = v;
                }
        }
        LGKM0();
        BAR();
        if (wk == 0) {
#pragma unroll
            for (int od = 0; od < 4; od++)
#pragma unroll
                for (int r4 = 0; r4 < 4; r4++) {
                    f32x4 m = *(const f32x4*)&Om[pid][od * 4 + r4][lane][0];
                    o[od][r4 * 4 + 0] += m[0]; o[od][r4 * 4 + 1] += m[1];
                    o[od][r4 * 4 + 2] += m[2]; o[od][r4 * 4 + 3] += m[3];
                }
            float rl[16];
#pragma unroll
            for (int r = 0; r < 16; r++) {
                int ql = (r & 3) + 8 * (r >> 2) + 4 * hi;
                rl[r] = 1.0f / (Ls[0][pid][ql] + Ls[1][pid][ql]);
            }
#pragma unroll
            for (int od = 0; od < 4; od++)
#pragma unroll
                for (int r = 0; r < 16; r++) {
                    int qg2 = q0 + chunk * 32 + (r & 3) + 8 * (r >> 2) + 4 * hi;
                    attn[(size_t)(b * 2048 + qg2) * 2048 + hgl * 128 + od * 32 + l31] =
                        f2bf(o[od][r] * rl[r]);
                }
        }
    }
}

// ---------------------------------------------------------------- launch
extern "C" void kernel_launch(void* const* d_in, const int* in_sizes, int n_in,
                              void* d_out, int out_size, void* d_ws, size_t ws_size,
                              hipStream_t stream) {
    (void)in_sizes; (void)n_in; (void)out_size; (void)ws_size;
    const float* hidden = (const float*)d_in[0];
    const float* cosb   = (const float*)d_in[1];
    const float* sinb   = (const float*)d_in[2];
    // d_in[3] = attention_mask: causal, computed inline
    const float* q_w    = (const float*)d_in[4];
    const float* k_w    = (const float*)d_in[5];
    const float* v_w    = (const float*)d_in[6];
    const float* o_w    = (const float*)d_in[7];

    char* ws = (char*)d_ws;                                  // 104 MB used
    ushort_t* hb   = (ushort_t*)(ws);                        // [4096][2048] bf16 hidden
    ushort_t* wqkv = (ushort_t*)(ws + (16ull << 20));        // [4096][2048] bf16 q|k|v weights
    ushort_t* owb  = (ushort_t*)(ws + (32ull << 20));        // [2048][2048] bf16 o_w
    ushort_t* qkv  = (ushort_t*)(ws + (40ull << 20));        // [4096][4096] bf16 qkv proj
    ushort_t* attn = qkv;                                    // alias: qkv consumed before flash
    ushort_t* qb   = (ushort_t*)(ws + (72ull << 20));        // [2][16][2048][128]
    ushort_t* kb   = (ushort_t*)(ws + (88ull << 20));        // [2][8][2048][128]
    ushort_t* vt   = (ushort_t*)(ws + (96ull << 20));        // [2][8][128][2048]

    convert_all<<<20480, 256, 0, stream>>>((const f32x4*)hidden, (const f32x4*)q_w,
                                           (const f32x4*)k_w, (const f32x4*)v_w,
                                           (const f32x4*)o_w,
                                           (us4*)hb, (us4*)wqkv, (us4*)owb);

    gemm256<ushort_t><<<256, 512, 0, stream>>>(hb, wqkv, qkv, 4096, 2048);
    rope_norm<<<dim3(4096, 6), 256, 0, stream>>>(qkv, cosb, sinb, qb, kb);
    v_transpose<<<dim3(32, 2, 16), 256, 0, stream>>>(qkv, vt);
    flash_attn<<<256, 512, 0, stream>>>(qb, kb, vt, attn);
    gemm256<float><<<128, 512, 0, stream>>>(attn, owb, (float*)d_out, 2048, 2048);
}

// Round 6
// 320.528 us; speedup vs baseline: 1.1629x; 1.0491x over previous
//
#include <hip/hip_runtime.h>

typedef unsigned short ushort_t;
typedef __bf16 bf16x8 __attribute__((ext_vector_type(8)));
typedef float f32x4 __attribute__((ext_vector_type(4)));
typedef float f32x16 __attribute__((ext_vector_type(16)));
typedef unsigned int u32x4 __attribute__((ext_vector_type(4)));
typedef unsigned short us4 __attribute__((ext_vector_type(4)));
typedef unsigned short us8 __attribute__((ext_vector_type(8)));

#define DEVINL __device__ __forceinline__

DEVINL ushort_t f2bf(float f) {
    unsigned u = __float_as_uint(f);
    u += 0x7FFF + ((u >> 16) & 1);   // RNE
    return (ushort_t)(u >> 16);
}
DEVINL float bf2f(ushort_t h) { return __uint_as_float(((unsigned)h) << 16); }

DEVINL void gload_lds16(const void* g, void* l) {
    __builtin_amdgcn_global_load_lds(
        (const __attribute__((address_space(1))) void*)g,
        (__attribute__((address_space(3))) void*)l, 16, 0, 0);
}

DEVINL bf16x8 ld_frag(const ushort_t* p) {
    us8 v = *(const us8*)p;
    return __builtin_bit_cast(bf16x8, v);
}

// pack 2 f32 -> u32 of 2 bf16 (lo = a, hi = b), RNE
DEVINL unsigned cvt_pk_bf16(float a, float b) {
    unsigned r;
    asm("v_cvt_pk_bf16_f32 %0, %1, %2" : "=v"(r) : "v"(a), "v"(b));
    return r;
}
// swap a's upper 32 lanes with b's lower 32 lanes (both modified)
#define PERMSWAP(a, b) asm volatile("v_permlane32_swap_b32 %0, %1" : "+v"(a), "+v"(b))

#define BAR()     asm volatile("s_barrier" ::: "memory")
#define LGKM0()   asm volatile("s_waitcnt lgkmcnt(0)" ::: "memory")
#define VMCNT(n)  asm volatile("s_waitcnt vmcnt(" #n ")" ::: "memory")
// Wait-THEN-barrier: drain own staging loads, then make tile globally visible.
#define BARRIER_DRAIN() asm volatile("s_waitcnt vmcnt(0)\n\ts_barrier" ::: "memory")

// ---------------------------------------------------------------- fused convert
__global__ __launch_bounds__(256) void convert_all(const f32x4* __restrict__ h,
                                                   const f32x4* __restrict__ qw,
                                                   const f32x4* __restrict__ kw,
                                                   const f32x4* __restrict__ vw,
                                                   const f32x4* __restrict__ ow,
                                                   us4* __restrict__ hb,
                                                   us4* __restrict__ wqkv,
                                                   us4* __restrict__ owb) {
    const int N0 = 2097152;              // hidden  (2*2048*2048 /4)
    const int N1 = 1048576;              // q_w     (2048*2048 /4)
    const int N2 = 524288;               // k_w
    const int N3 = 524288;               // v_w
    int i = blockIdx.x * 256 + threadIdx.x;
    const f32x4* src; us4* dst;
    if (i < N0)                               { src = h  + i;                 dst = hb + i; }
    else if ((i -= N0) < N1)                  { src = qw + i;                 dst = wqkv + i; }
    else if ((i -= N1) < N2)                  { src = kw + i;                 dst = wqkv + 1048576 + i; }
    else if ((i -= N2) < N3)                  { src = vw + i;                 dst = wqkv + 1572864 + i; }
    else                                      { i -= N3; src = ow + i;       dst = owb + i; }
    f32x4 f = *src;
    us4 o;
    o[0] = f2bf(f[0]); o[1] = f2bf(f[1]); o[2] = f2bf(f[2]); o[3] = f2bf(f[3]);
    *dst = o;
}

// ---------------------------------------------------------------- GEMM C = A @ W^T
// 256x256 tile, BK=64, 8 waves (2x4), 8-phase schedule (T2+T3+T4+T5).
// VERIFIED round-4 version (16/0/8/0 reads). Stage stream: P1:A1(t+1),
// P2:B0(t+2), P3:B1(t+2), P4:A0(t+2), vmcnt(6)@P4. NOTE: LDS half-liveness —
// half 0 of As/Bs is only fully read after P3 (wave wm=0 reads rows 64..127
// there), so A0 can ONLY be staged at P4. Do not move it earlier.
template <typename OutT>
__global__ __launch_bounds__(512, 2) void gemm256(const ushort_t* __restrict__ A,
                                                  const ushort_t* __restrict__ W,
                                                  OutT* __restrict__ C,
                                                  int N, int K) {
    __shared__ ushort_t As[2][256 * 64];
    __shared__ ushort_t Bs[2][256 * 64];
    const int t = threadIdx.x;
    const int lane = t & 63;
    const int quad = lane >> 4, l16 = lane & 15;
    const int wm = t >> 8, wn = (t >> 6) & 3;        // 2 x 4 wave grid

    int bid = blockIdx.x;
    int xcd = bid & 7, j = bid >> 3;
    int tm, tn;
    if (N == 4096) { tm = (xcd >> 1) * 4 + (j >> 3); tn = (xcd & 1) * 8 + (j & 7); }
    else           { tm = xcd * 2 + (j >> 3);        tn = j & 7; }
    const int bm = tm * 256, bn = tn * 256;

    const int srow0 = t >> 3;                        // rows 0..63
    const int sg0 = ((t & 7) ^ (srow0 & 7)) * 8;     // inverse-swizzled src col
    const int srow1 = srow0 + 64;                    // rows 64..127
    const int sg1 = ((t & 7) ^ (srow1 & 7)) * 8;

    auto stageA = [&](int buf, int half, int k0) {
        gload_lds16(A + (size_t)(bm + half * 128 + srow0) * K + k0 + sg0,
                    &As[buf][half * 8192 + t * 8]);
        gload_lds16(A + (size_t)(bm + half * 128 + srow1) * K + k0 + sg1,
                    &As[buf][half * 8192 + 4096 + t * 8]);
    };
    auto stageB = [&](int buf, int half, int k0) {
        gload_lds16(W + (size_t)(bn + half * 128 + srow0) * K + k0 + sg0,
                    &Bs[buf][half * 8192 + t * 8]);
        gload_lds16(W + (size_t)(bn + half * 128 + srow1) * K + k0 + sg1,
                    &Bs[buf][half * 8192 + 4096 + t * 8]);
    };

    const int xsw = l16 & 7;
    const int arow = (wm * 128 + l16) * 64;
    const int brow = (wn * 64 + l16) * 64;
    const int ac0 = ((0 + quad) ^ xsw) * 8;          // kk=0 granule offset
    const int ac1 = ((4 + quad) ^ xsw) * 8;          // kk=1

    auto ldA = [&](int buf, int mf, int kk) {
        return ld_frag(&As[buf][arow + mf * 1024 + (kk ? ac1 : ac0)]);
    };
    auto ldB = [&](int buf, int nf, int kk) {
        return ld_frag(&Bs[buf][brow + nf * 1024 + (kk ? ac1 : ac0)]);
    };

    f32x4 acc[8][4];
#pragma unroll
    for (int i = 0; i < 8; i++)
#pragma unroll
        for (int jj = 0; jj < 4; jj++) acc[i][jj] = f32x4{0.f, 0.f, 0.f, 0.f};

    const int NIT = K >> 6;
    stageA(0, 0, 0); stageA(0, 1, 0); stageB(0, 0, 0); stageB(0, 1, 0);
    VMCNT(4);
    stageB(1, 0, 64); stageB(1, 1, 64); stageA(1, 0, 64);
    VMCNT(6);
    BAR();

    bf16x8 a[4][2], b[4][2];
    for (int tt = 0; tt < NIT; ++tt) {
        const int buf = tt & 1;
        const int k2 = (tt + 2) << 6;

        // ---- phase 1: quadrant (m-lo, n-lo). Read A-lo (8) + all B (8).
#pragma unroll
        for (int mt = 0; mt < 4; mt++) { a[mt][0] = ldA(buf, mt, 0); a[mt][1] = ldA(buf, mt, 1); }
#pragma unroll
        for (int nt = 0; nt < 4; nt++) { b[nt][0] = ldB(buf, nt, 0); b[nt][1] = ldB(buf, nt, 1); }
        if (tt + 1 < NIT) stageA(buf ^ 1, 1, (tt + 1) << 6);
        BAR(); LGKM0();
        __builtin_amdgcn_s_setprio(1);
#pragma unroll
        for (int mt = 0; mt < 4; mt++)
#pragma unroll
            for (int nt = 0; nt < 2; nt++)
#pragma unroll
                for (int kk = 0; kk < 2; kk++)
                    acc[mt][nt] = __builtin_amdgcn_mfma_f32_16x16x32_bf16(a[mt][kk], b[nt][kk], acc[mt][nt], 0, 0, 0);
        __builtin_amdgcn_s_setprio(0);
        LGKM0();
        BAR();

        // ---- phase 2: (m-lo, n-hi). B0 region fully consumed in P1.
        if (tt + 2 < NIT) stageB(buf, 0, k2);
        BAR();
        __builtin_amdgcn_s_setprio(1);
#pragma unroll
        for (int mt = 0; mt < 4; mt++)
#pragma unroll
            for (int nt = 0; nt < 2; nt++)
#pragma unroll
                for (int kk = 0; kk < 2; kk++)
                    acc[mt][2 + nt] = __builtin_amdgcn_mfma_f32_16x16x32_bf16(a[mt][kk], b[2 + nt][kk], acc[mt][2 + nt], 0, 0, 0);
        __builtin_amdgcn_s_setprio(0);
        BAR();

        // ---- phase 3: (m-hi, n-lo). Read A-hi (8).
#pragma unroll
        for (int mt = 0; mt < 4; mt++) { a[mt][0] = ldA(buf, 4 + mt, 0); a[mt][1] = ldA(buf, 4 + mt, 1); }
        if (tt + 2 < NIT) stageB(buf, 1, k2);
        BAR(); LGKM0();
        __builtin_amdgcn_s_setprio(1);
#pragma unroll
        for (int mt = 0; mt < 4; mt++)
#pragma unroll
            for (int nt = 0; nt < 2; nt++)
#pragma unroll
                for (int kk = 0; kk < 2; kk++)
                    acc[4 + mt][nt] = __builtin_amdgcn_mfma_f32_16x16x32_bf16(a[mt][kk], b[nt][kk], acc[4 + mt][nt], 0, 0, 0);
        __builtin_amdgcn_s_setprio(0);
        BAR();

        // ---- phase 4: (m-hi, n-hi). A0 region consumed by end of P3.
        if (tt + 2 < NIT)      { stageA(buf, 0, k2); VMCNT(6); }
        else if (tt + 1 < NIT) { VMCNT(0); }
        BAR();
        __builtin_amdgcn_s_setprio(1);
#pragma unroll
        for (int mt = 0; mt < 4; mt++)
#pragma unroll
            for (int nt = 0; nt < 2; nt++)
#pragma unroll
                for (int kk = 0; kk < 2; kk++)
                    acc[4 + mt][2 + nt] = __builtin_amdgcn_mfma_f32_16x16x32_bf16(a[mt][kk], b[2 + nt][kk], acc[4 + mt][2 + nt], 0, 0, 0);
        __builtin_amdgcn_s_setprio(0);
        BAR();
    }

#pragma unroll
    for (int mf = 0; mf < 8; mf++)
#pragma unroll
        for (int nf = 0; nf < 4; nf++) {
            const int row = bm + wm * 128 + mf * 16 + quad * 4;
            const int col = bn + wn * 64 + nf * 16 + l16;
#pragma unroll
            for (int rr = 0; rr < 4; rr++) {
                float v = acc[mf][nf][rr];
                if constexpr (sizeof(OutT) == 2)
                    C[(size_t)(row + rr) * N + col] = (OutT)f2bf(v);
                else
                    C[(size_t)(row + rr) * N + col] = v;
            }
        }
}

// ---------------------------------------------------------------- O-proj GEMM
// 256x128 tile, BK=64, 8 waves (4x2), wave = 64x64, 4 phases x 8 MFMA.
// Grid = 16 x 16 = 256 blocks -> 1 block/CU (the old 256x256 version had only
// 128 blocks: half the GPU idle). Reads 8/4/4/0 per phase.
// Half-liveness: B fully read after P2 -> stage B(t+2) at P3; A fully read
// after P3 -> stage A0+A1(t+2) at P4. vmcnt ledger: 6 outstanding + 2@P3 +
// 4@P4 = 12; vmcnt(6) drains exactly tile t+1's 6.
__global__ __launch_bounds__(512, 2) void gemm_o(const ushort_t* __restrict__ A,
                                                 const ushort_t* __restrict__ W,
                                                 float* __restrict__ C,
                                                 int N, int K) {
    __shared__ ushort_t As[2][256 * 64];             // 32 KB each
    __shared__ ushort_t Bs[2][128 * 64];             // 16 KB each
    const int t = threadIdx.x;
    const int lane = t & 63;
    const int quad = lane >> 4, l16 = lane & 15;
    const int wm = t >> 7, wn = (t >> 6) & 1;        // 4 x 2 wave grid

    int bid = blockIdx.x;
    int xcd = bid & 7, j = bid >> 3;
    const int tm = (xcd >> 1) * 4 + (j >> 3);
    const int tn = (xcd & 1) * 8 + (j & 7);
    const int bm = tm * 256, bn = tn * 128;

    const int srow0 = t >> 3;                        // rows 0..63
    const int sg0 = ((t & 7) ^ (srow0 & 7)) * 8;
    const int srow1 = srow0 + 64;                    // rows 64..127
    const int sg1 = ((t & 7) ^ (srow1 & 7)) * 8;

    auto stageA = [&](int buf, int half, int k0) {
        gload_lds16(A + (size_t)(bm + half * 128 + srow0) * K + k0 + sg0,
                    &As[buf][half * 8192 + t * 8]);
        gload_lds16(A + (size_t)(bm + half * 128 + srow1) * K + k0 + sg1,
                    &As[buf][half * 8192 + 4096 + t * 8]);
    };
    auto stageB = [&](int buf, int k0) {
        gload_lds16(W + (size_t)(bn + srow0) * K + k0 + sg0, &Bs[buf][t * 8]);
        gload_lds16(W + (size_t)(bn + srow1) * K + k0 + sg1, &Bs[buf][4096 + t * 8]);
    };

    const int xsw = l16 & 7;
    const int arow = (wm * 64 + l16) * 64;
    const int brow = (wn * 64 + l16) * 64;
    const int ac0 = ((0 + quad) ^ xsw) * 8;
    const int ac1 = ((4 + quad) ^ xsw) * 8;

    auto ldA = [&](int buf, int mf, int kk) {
        return ld_frag(&As[buf][arow + mf * 1024 + (kk ? ac1 : ac0)]);
    };
    auto ldB = [&](int buf, int nf, int kk) {
        return ld_frag(&Bs[buf][brow + nf * 1024 + (kk ? ac1 : ac0)]);
    };

    f32x4 acc[4][4];
#pragma unroll
    for (int i = 0; i < 4; i++)
#pragma unroll
        for (int jj = 0; jj < 4; jj++) acc[i][jj] = f32x4{0.f, 0.f, 0.f, 0.f};

    const int NIT = K >> 6;
    // prologue: tile0 (6 loads) + tile1 (6 loads); vmcnt(6) drains tile0.
    stageA(0, 0, 0); stageA(0, 1, 0); stageB(0, 0);
    stageA(1, 0, 64); stageA(1, 1, 64); stageB(1, 64);
    VMCNT(6);
    BAR();

    bf16x8 a[2][2], bl[2][2], bh[2][2];
    for (int tt = 0; tt < NIT; ++tt) {
        const int buf = tt & 1;
        const int k2 = (tt + 2) << 6;

        // ---- phase 1: (m-lo, n-lo). Read a-lo (4) + b-lo (4).
#pragma unroll
        for (int mt = 0; mt < 2; mt++) { a[mt][0] = ldA(buf, mt, 0); a[mt][1] = ldA(buf, mt, 1); }
#pragma unroll
        for (int nt = 0; nt < 2; nt++) { bl[nt][0] = ldB(buf, nt, 0); bl[nt][1] = ldB(buf, nt, 1); }
        BAR(); LGKM0();
        __builtin_amdgcn_s_setprio(1);
#pragma unroll
        for (int mt = 0; mt < 2; mt++)
#pragma unroll
            for (int nt = 0; nt < 2; nt++)
#pragma unroll
                for (int kk = 0; kk < 2; kk++)
                    acc[mt][nt] = __builtin_amdgcn_mfma_f32_16x16x32_bf16(a[mt][kk], bl[nt][kk], acc[mt][nt], 0, 0, 0);
        __builtin_amdgcn_s_setprio(0);
        BAR();

        // ---- phase 2: (m-lo, n-hi). Read b-hi (4).
#pragma unroll
        for (int nt = 0; nt < 2; nt++) { bh[nt][0] = ldB(buf, 2 + nt, 0); bh[nt][1] = ldB(buf, 2 + nt, 1); }
        BAR(); LGKM0();
        __builtin_amdgcn_s_setprio(1);
#pragma unroll
        for (int mt = 0; mt < 2; mt++)
#pragma unroll
            for (int nt = 0; nt < 2; nt++)
#pragma unroll
                for (int kk = 0; kk < 2; kk++)
                    acc[mt][2 + nt] = __builtin_amdgcn_mfma_f32_16x16x32_bf16(a[mt][kk], bh[nt][kk], acc[mt][2 + nt], 0, 0, 0);
        __builtin_amdgcn_s_setprio(0);
        BAR();

        // ---- phase 3: (m-hi, n-lo). Read a-hi (4). Stage B(t+2) (B drained @P2).
#pragma unroll
        for (int mt = 0; mt < 2; mt++) { a[mt][0] = ldA(buf, 2 + mt, 0); a[mt][1] = ldA(buf, 2 + mt, 1); }
        if (tt + 2 < NIT) stageB(buf, k2);
        BAR(); LGKM0();
        __builtin_amdgcn_s_setprio(1);
#pragma unroll
        for (int mt = 0; mt < 2; mt++)
#pragma unroll
            for (int nt = 0; nt < 2; nt++)
#pragma unroll
                for (int kk = 0; kk < 2; kk++)
                    acc[2 + mt][nt] = __builtin_amdgcn_mfma_f32_16x16x32_bf16(a[mt][kk], bl[nt][kk], acc[2 + mt][nt], 0, 0, 0);
        __builtin_amdgcn_s_setprio(0);
        BAR();

        // ---- phase 4: (m-hi, n-hi). Stage A0,A1(t+2) (A drained @P3); vmcnt(6).
        if (tt + 2 < NIT)      { stageA(buf, 0, k2); stageA(buf, 1, k2); VMCNT(6); }
        else if (tt + 1 < NIT) { VMCNT(0); }
        BAR();
        __builtin_amdgcn_s_setprio(1);
#pragma unroll
        for (int mt = 0; mt < 2; mt++)
#pragma unroll
            for (int nt = 0; nt < 2; nt++)
#pragma unroll
                for (int kk = 0; kk < 2; kk++)
                    acc[2 + mt][2 + nt] = __builtin_amdgcn_mfma_f32_16x16x32_bf16(a[mt][kk], bh[nt][kk], acc[2 + mt][2 + nt], 0, 0, 0);
        __builtin_amdgcn_s_setprio(0);
        BAR();
    }

#pragma unroll
    for (int mf = 0; mf < 4; mf++)
#pragma unroll
        for (int nf = 0; nf < 4; nf++) {
            const int row = bm + wm * 64 + mf * 16 + quad * 4;
            const int col = bn + wn * 64 + nf * 16 + l16;
#pragma unroll
            for (int rr = 0; rr < 4; rr++)
                C[(size_t)(row + rr) * N + col] = acc[mf][nf][rr];
        }
}

// ---------------------------------------------------------------- RoPE + l2norm
__global__ __launch_bounds__(256) void rope_norm(const ushort_t* __restrict__ qkv,
                                                 const float* __restrict__ cosb,
                                                 const float* __restrict__ sinb,
                                                 ushort_t* __restrict__ q,
                                                 ushort_t* __restrict__ k) {
    int row = blockIdx.x;                 // b*2048 + s
    int b = row >> 11, s = row & 2047;
    int w = threadIdx.x >> 6, lane = threadIdx.x & 63;
    int hh = blockIdx.y * 4 + w;          // 0..23
    const ushort_t* src = qkv + (size_t)row * 4096 + hh * 128;
    float x1 = bf2f(src[lane]);
    float x2 = bf2f(src[lane + 64]);
    float c = cosb[(size_t)row * 128 + lane];
    float sn = sinb[(size_t)row * 128 + lane];
    float y1 = x1 * c + x2 * sn;
    float y2 = x2 * c - x1 * sn;
    float ss = y1 * y1 + y2 * y2;
#pragma unroll
    for (int off = 1; off < 64; off <<= 1) ss += __shfl_xor(ss, off);
    float rinv = rsqrtf(ss * (1.0f / 128.0f) + 1e-6f);
    y1 *= rinv; y2 *= rinv;
    ushort_t* dst;
    if (hh < 16) dst = q + (((size_t)(b * 16 + hh)) * 2048 + s) * 128;
    else         dst = k + (((size_t)(b * 8 + hh - 16)) * 2048 + s) * 128;
    dst[lane] = f2bf(y1);
    dst[lane + 64] = f2bf(y2);
}

// ---------------------------------------------------------------- V transpose
__global__ __launch_bounds__(256) void v_transpose(const ushort_t* __restrict__ qkv,
                                                   ushort_t* __restrict__ vt) {
    __shared__ ushort_t tile[64 * 72];
    int t = threadIdx.x;
    int s0 = blockIdx.x * 64, d0 = blockIdx.y * 64, bh = blockIdx.z;
    int b = bh >> 3, kvh = bh & 7;
    {
        int sl = t >> 2, c = t & 3;
        const ushort_t* src = qkv + (size_t)(b * 2048 + s0 + sl) * 4096 + 3072 + kvh * 128 + d0 + c * 16;
        u32x4 v0 = *(const u32x4*)src;
        u32x4 v1 = *(const u32x4*)(src + 8);
        *(u32x4*)&tile[sl * 72 + c * 16] = v0;
        *(u32x4*)&tile[sl * 72 + c * 16 + 8] = v1;
    }
    __syncthreads();
    {
        int dl = t >> 2, c = t & 3;
        alignas(16) ushort_t tmp[16];
#pragma unroll
        for (int i = 0; i < 16; i++) tmp[i] = tile[(c * 16 + i) * 72 + dl];
        ushort_t* dst = vt + (size_t)(bh * 128 + d0 + dl) * 2048 + s0 + c * 16;
        *(u32x4*)dst = *(const u32x4*)&tmp[0];
        *(u32x4*)(dst + 8) = *(const u32x4*)&tmp[8];
    }
}

// ---------------------------------------------------------------- Flash attention
// v4 (unchanged, verified): 32x32 MFMA, swapped QK^T -> P lane-local; cvt_pk +
// permlane32_swap builds PV A-frag in registers. One barrier per iteration.
__global__ __launch_bounds__(512, 2) void flash_attn(const ushort_t* __restrict__ q,
                                                     const ushort_t* __restrict__ k,
                                                     const ushort_t* __restrict__ vt,
                                                     ushort_t* __restrict__ attn) {
    __shared__ ushort_t Ks[2][4 * 64 * 32];      // 2 x 16 KB  [qd][64 kv][32]
    __shared__ ushort_t Vts[2][2 * 128 * 32];    // 2 x 16 KB  [ks][128 d][32 kv]
    __shared__ float    Om[4][16][64][4];        // 64 KB o-merge scratch
    __shared__ float    Ls[2][4][32];            // lsum partials [wk][pid][qrow]
    const int t = threadIdx.x;
    const int w = t >> 6, lane = t & 63;
    const int wh = w & 1, chunk = (w >> 1) & 1, wk = w >> 2;
    const int pid = chunk * 2 + wh;
    const int l31 = lane & 31, hi = lane >> 5;
    const int swz = (l31 >> 1) & 3;
    const int lid = blockIdx.x;
    const int xcd = lid & 7, jj = lid >> 3;
    const int g = xcd * 2 + (jj >> 4);           // (b,kvh) group, 2 per XCD
    const int p = jj & 15;                       // q-tile pair index 0..15
    const int b = g >> 3, kvh = g & 7;
    const int h0 = kvh * 2;
    const size_t kbase = ((size_t)(b * 8 + kvh)) * 2048 * 128;
    const size_t vbase = ((size_t)(b * 8 + kvh)) * 128 * 2048;

    const float C1 = 0.12751744f;   // (1/sqrt(128)) * log2(e)
    const float C2 = 1.45f;         // fixed max in log2 domain

    auto stage = [&](int j0, int buf) {
#pragma unroll
        for (int i = 0; i < 2; i++) {            // K tile (16KB)
            int u = i * 512 + t;
            int qd = u >> 8, rr = (u >> 2) & 63;
            int c4 = ((u & 3) ^ ((rr >> 1) & 3)) * 8;
            gload_lds16(k + kbase + (size_t)(j0 + rr) * 128 + qd * 32 + c4,
                        (char*)Ks[buf] + u * 16);
        }
#pragma unroll
        for (int i = 0; i < 2; i++) {            // Vt tile (16KB)
            int u = i * 512 + t;
            int ks = u >> 9, dd = (u >> 2) & 127;
            int c4 = ((u & 3) ^ ((dd >> 1) & 3)) * 8;
            gload_lds16(vt + vbase + (size_t)dd * 2048 + j0 + ks * 32 + c4,
                        (char*)Vts[buf] + u * 16);
        }
    };

    const int qtile0 = 31 - p;                   // heavy pass first
    const int S_total = qtile0 + 1 + p + 1;      // tile-stream length (=33)
    auto j0_of = [&](int s) { return (s <= qtile0 ? s : s - qtile0 - 1) * 64; };

    stage(j0_of(0), 0);
    int sidx = 0;

    for (int pass = 0; pass < 2; ++pass) {
        const int qi = pass ? p : qtile0;
        const int q0 = qi * 64;
        const int hgl = h0 + wh;
        const int qg = q0 + chunk * 32 + l31;    // this lane's q-row (B side)

        bf16x8 qf[8];
        {
            const size_t qrow = ((size_t)(b * 16 + hgl) * 2048 + qg) * 128;
#pragma unroll
            for (int s = 0; s < 8; s++) {
                us8 v = *(const us8*)(q + qrow + s * 16 + hi * 8);
                qf[s] = __builtin_bit_cast(bf16x8, v);
            }
        }

        f32x16 o[4];
#pragma unroll
        for (int i = 0; i < 4; i++)
#pragma unroll
            for (int r = 0; r < 16; r++) o[i][r] = 0.f;
        float lsum = 0.f;

        for (int jt = 0; jt <= qi; ++jt) {
            const int j0 = jt * 64;
            const bool diag = (jt == qi);
            const int buf = sidx & 1;
            BARRIER_DRAIN();                     // drain own tile-sidx loads; tile visible
            if (sidx + 1 < S_total) stage(j0_of(sidx + 1), buf ^ 1);
            sidx++;

            // ---- QK^T swapped: sc = K(32kv) x Q(32q), k-dim = d = 128
            f32x16 sc;
#pragma unroll
            for (int r = 0; r < 16; r++) sc[r] = 0.f;
            __builtin_amdgcn_s_setprio(1);
#pragma unroll
            for (int s = 0; s < 8; s++) {
                bf16x8 kf = ld_frag(&Ks[buf][(s >> 1) * 2048 + (wk * 32 + l31) * 32 +
                                             (((((s & 1) << 1) | hi)) ^ swz) * 8]);
                sc = __builtin_amdgcn_mfma_f32_32x32x16_bf16(kf, qf[s], sc, 0, 0, 0);
            }
            __builtin_amdgcn_s_setprio(0);

            // ---- softmax in-register
#pragma unroll
            for (int r = 0; r < 16; r++)
                sc[r] = __builtin_amdgcn_exp2f(sc[r] * C1 - C2);
            if (diag) {
                const int kvb = j0 + wk * 32 + 4 * hi;
#pragma unroll
                for (int r = 0; r < 16; r++) {
                    int kg = kvb + (r & 3) + 8 * (r >> 2);
                    if (kg > qg) sc[r] = 0.f;
                }
            }
#pragma unroll
            for (int r = 0; r < 16; r++) lsum += sc[r];

            // ---- pack P -> PV A-frags via cvt_pk + permlane32_swap
            bf16x8 pf[2];
#pragma unroll
            for (int kp = 0; kp < 2; kp++) {
                const int rb = kp * 8;
                unsigned x0 = cvt_pk_bf16(sc[rb + 0], sc[rb + 1]);
                unsigned x1 = cvt_pk_bf16(sc[rb + 2], sc[rb + 3]);
                unsigned y0 = cvt_pk_bf16(sc[rb + 4], sc[rb + 5]);
                unsigned y1 = cvt_pk_bf16(sc[rb + 6], sc[rb + 7]);
                PERMSWAP(x0, y0);
                PERMSWAP(x1, y1);
                u32x4 pv; pv[0] = x0; pv[1] = x1; pv[2] = y0; pv[3] = y1;
                pf[kp] = __builtin_bit_cast(bf16x8, pv);
            }

            // ---- PV
            __builtin_amdgcn_s_setprio(1);
#pragma unroll
            for (int kp = 0; kp < 2; kp++)
#pragma unroll
                for (int od = 0; od < 4; od++) {
                    bf16x8 vf = ld_frag(&Vts[buf][wk * 4096 + (od * 32 + l31) * 32 +
                                                  ((((kp << 1) | hi)) ^ swz) * 8]);
                    o[od] = __builtin_amdgcn_mfma_f32_32x32x16_bf16(pf[kp], vf, o[od], 0, 0, 0);
                }
            __builtin_amdgcn_s_setprio(0);
        }

        // ---- pass epilogue: merge kv-halves, normalize, store
        lsum += __shfl_xor(lsum, 32);
        if (hi == 0) Ls[wk][pid][l31] = lsum;
        if (wk == 1) {
#pragma unroll
            for (int od = 0; od < 4; od++)
#pragma unroll
                for (int r4 = 0; r4 < 4; r4++) {
                    f32x4 v;
                    v[0] = o[od][r4 * 4 + 0]; v[1] = o[od][r4 * 4 + 1];
                    v[2] = o[od][r4 * 4 + 2]; v[3] = o[od][r4 * 4 + 3];
                    *(f32x4*)&Om[pid][od * 4 + r4][lane][0] = v;
                }
        }
        LGKM0();
        BAR();
        if (wk == 0) {
#pragma unroll
            for (int od = 0; od < 4; od++)
#pragma unroll
                for (int r4 = 0; r4 < 4; r4++) {
                    f32x4 m = *(const f32x4*)&Om[pid][od * 4 + r4][lane][0];
                    o[od][r4 * 4 + 0] += m[0]; o[od][r4 * 4 + 1] += m[1];
                    o[od][r4 * 4 + 2] += m[2]; o[od][r4 * 4 + 3] += m[3];
                }
            float rl[16];
#pragma unroll
            for (int r = 0; r < 16; r++) {
                int ql = (r & 3) + 8 * (r >> 2) + 4 * hi;
                rl[r] = 1.0f / (Ls[0][pid][ql] + Ls[1][pid][ql]);
            }
#pragma unroll
            for (int od = 0; od < 4; od++)
#pragma unroll
                for (int r = 0; r < 16; r++) {
                    int qg2 = q0 + chunk * 32 + (r & 3) + 8 * (r >> 2) + 4 * hi;
                    attn[(size_t)(b * 2048 + qg2) * 2048 + hgl * 128 + od * 32 + l31] =
                        f2bf(o[od][r] * rl[r]);
                }
        }
    }
}

// ---------------------------------------------------------------- launch
extern "C" void kernel_launch(void* const* d_in, const int* in_sizes, int n_in,
                              void* d_out, int out_size, void* d_ws, size_t ws_size,
                              hipStream_t stream) {
    (void)in_sizes; (void)n_in; (void)out_size; (void)ws_size;
    const float* hidden = (const float*)d_in[0];
    const float* cosb   = (const float*)d_in[1];
    const float* sinb   = (const float*)d_in[2];
    // d_in[3] = attention_mask: causal, computed inline
    const float* q_w    = (const float*)d_in[4];
    const float* k_w    = (const float*)d_in[5];
    const float* v_w    = (const float*)d_in[6];
    const float* o_w    = (const float*)d_in[7];

    char* ws = (char*)d_ws;                                  // 104 MB used
    ushort_t* hb   = (ushort_t*)(ws);                        // [4096][2048] bf16 hidden
    ushort_t* wqkv = (ushort_t*)(ws + (16ull << 20));        // [4096][2048] bf16 q|k|v weights
    ushort_t* owb  = (ushort_t*)(ws + (32ull << 20));        // [2048][2048] bf16 o_w
    ushort_t* qkv  = (ushort_t*)(ws + (40ull << 20));        // [4096][4096] bf16 qkv proj
    ushort_t* attn = qkv;                                    // alias: qkv consumed before flash
    ushort_t* qb   = (ushort_t*)(ws + (72ull << 20));        // [2][16][2048][128]
    ushort_t* kb   = (ushort_t*)(ws + (88ull << 20));        // [2][8][2048][128]
    ushort_t* vt   = (ushort_t*)(ws + (96ull << 20));        // [2][8][128][2048]

    convert_all<<<20480, 256, 0, stream>>>((const f32x4*)hidden, (const f32x4*)q_w,
                                           (const f32x4*)k_w, (const f32x4*)v_w,
                                           (const f32x4*)o_w,
                                           (us4*)hb, (us4*)wqkv, (us4*)owb);

    gemm256<ushort_t><<<256, 512, 0, stream>>>(hb, wqkv, qkv, 4096, 2048);
    rope_norm<<<dim3(4096, 6), 256, 0, stream>>>(qkv, cosb, sinb, qb, kb);
    v_transpose<<<dim3(32, 2, 16), 256, 0, stream>>>(qkv, vt);
    flash_attn<<<256, 512, 0, stream>>>(qb, kb, vt, attn);
    gemm_o<<<256, 512, 0, stream>>>(attn, owb, (float*)d_out, 2048, 2048);
}

// Round 7
// 318.926 us; speedup vs baseline: 1.1687x; 1.0050x over previous
//
#include <hip/hip_runtime.h>

typedef unsigned short ushort_t;
typedef __bf16 bf16x8 __attribute__((ext_vector_type(8)));
typedef float f32x4 __attribute__((ext_vector_type(4)));
typedef float f32x16 __attribute__((ext_vector_type(16)));
typedef unsigned int u32x4 __attribute__((ext_vector_type(4)));
typedef unsigned short us4 __attribute__((ext_vector_type(4)));
typedef unsigned short us8 __attribute__((ext_vector_type(8)));

#define DEVINL __device__ __forceinline__

DEVINL ushort_t f2bf(float f) {
    unsigned u = __float_as_uint(f);
    u += 0x7FFF + ((u >> 16) & 1);   // RNE
    return (ushort_t)(u >> 16);
}
DEVINL float bf2f(ushort_t h) { return __uint_as_float(((unsigned)h) << 16); }

DEVINL void gload_lds16(const void* g, void* l) {
    __builtin_amdgcn_global_load_lds(
        (const __attribute__((address_space(1))) void*)g,
        (__attribute__((address_space(3))) void*)l, 16, 0, 0);
}

DEVINL bf16x8 ld_frag(const ushort_t* p) {
    us8 v = *(const us8*)p;
    return __builtin_bit_cast(bf16x8, v);
}

// pack 2 f32 -> u32 of 2 bf16 (lo = a, hi = b), RNE
DEVINL unsigned cvt_pk_bf16(float a, float b) {
    unsigned r;
    asm("v_cvt_pk_bf16_f32 %0, %1, %2" : "=v"(r) : "v"(a), "v"(b));
    return r;
}
// swap a's upper 32 lanes with b's lower 32 lanes (both modified)
#define PERMSWAP(a, b) asm volatile("v_permlane32_swap_b32 %0, %1" : "+v"(a), "+v"(b))

#define BAR()     asm volatile("s_barrier" ::: "memory")
#define LGKM0()   asm volatile("s_waitcnt lgkmcnt(0)" ::: "memory")
#define VMCNT(n)  asm volatile("s_waitcnt vmcnt(" #n ")" ::: "memory")
// Wait-THEN-barrier: drain own staging loads, then make tile globally visible.
#define BARRIER_DRAIN() asm volatile("s_waitcnt vmcnt(0)\n\ts_barrier" ::: "memory")

// ---------------------------------------------------------------- fused convert
__global__ __launch_bounds__(256) void convert_all(const f32x4* __restrict__ h,
                                                   const f32x4* __restrict__ qw,
                                                   const f32x4* __restrict__ kw,
                                                   const f32x4* __restrict__ vw,
                                                   const f32x4* __restrict__ ow,
                                                   us4* __restrict__ hb,
                                                   us4* __restrict__ wqkv,
                                                   us4* __restrict__ owb) {
    const int N0 = 2097152;              // hidden  (2*2048*2048 /4)
    const int N1 = 1048576;              // q_w     (2048*2048 /4)
    const int N2 = 524288;               // k_w
    const int N3 = 524288;               // v_w
    int i = blockIdx.x * 256 + threadIdx.x;
    const f32x4* src; us4* dst;
    if (i < N0)                               { src = h  + i;                 dst = hb + i; }
    else if ((i -= N0) < N1)                  { src = qw + i;                 dst = wqkv + i; }
    else if ((i -= N1) < N2)                  { src = kw + i;                 dst = wqkv + 1048576 + i; }
    else if ((i -= N2) < N3)                  { src = vw + i;                 dst = wqkv + 1572864 + i; }
    else                                      { i -= N3; src = ow + i;       dst = owb + i; }
    f32x4 f = *src;
    us4 o;
    o[0] = f2bf(f[0]); o[1] = f2bf(f[1]); o[2] = f2bf(f[2]); o[3] = f2bf(f[3]);
    *dst = o;
}

// ---------------------------------------------------------------- GEMM C = A @ W^T
// 256x256 tile, BK=64, 8 waves (2x4), 4 phases x 16 MFMA.
// BALANCED ds_reads 12/8/4/0 (was 16/0/8/0): P1 a-lo+b-lo, P2 a-hi, P3 b-hi.
// Requires separate al/ah register arrays (a-lo stays live through P3).
// Region liveness from ACTUAL row spans (wave grid 2x4):
//   A half h = wm=h's a-lo(P1) U a-hi(P2) -> A fully read after P2
//   B half h = wn-pair's b-lo(P1) U b-hi(P3) -> B fully read after P3
// Stage stream: P1:A1(t+1) [other buf], P3:A0(t+2), P4:B0(t+2)+B1(t+2).
// vmcnt@P4: older-than-A1(t+1) all drained by keeping {A0,B0,B1}(t+2)=6.
template <typename OutT>
__global__ __launch_bounds__(512, 2) void gemm256(const ushort_t* __restrict__ A,
                                                  const ushort_t* __restrict__ W,
                                                  OutT* __restrict__ C,
                                                  int N, int K) {
    __shared__ ushort_t As[2][256 * 64];
    __shared__ ushort_t Bs[2][256 * 64];
    const int t = threadIdx.x;
    const int lane = t & 63;
    const int quad = lane >> 4, l16 = lane & 15;
    const int wm = t >> 8, wn = (t >> 6) & 3;        // 2 x 4 wave grid

    int bid = blockIdx.x;
    int xcd = bid & 7, j = bid >> 3;
    int tm, tn;
    if (N == 4096) { tm = (xcd >> 1) * 4 + (j >> 3); tn = (xcd & 1) * 8 + (j & 7); }
    else           { tm = xcd * 2 + (j >> 3);        tn = j & 7; }
    const int bm = tm * 256, bn = tn * 256;

    const int srow0 = t >> 3;                        // rows 0..63
    const int sg0 = ((t & 7) ^ (srow0 & 7)) * 8;     // inverse-swizzled src col
    const int srow1 = srow0 + 64;                    // rows 64..127
    const int sg1 = ((t & 7) ^ (srow1 & 7)) * 8;

    auto stageA = [&](int buf, int half, int k0) {
        gload_lds16(A + (size_t)(bm + half * 128 + srow0) * K + k0 + sg0,
                    &As[buf][half * 8192 + t * 8]);
        gload_lds16(A + (size_t)(bm + half * 128 + srow1) * K + k0 + sg1,
                    &As[buf][half * 8192 + 4096 + t * 8]);
    };
    auto stageB = [&](int buf, int half, int k0) {
        gload_lds16(W + (size_t)(bn + half * 128 + srow0) * K + k0 + sg0,
                    &Bs[buf][half * 8192 + t * 8]);
        gload_lds16(W + (size_t)(bn + half * 128 + srow1) * K + k0 + sg1,
                    &Bs[buf][half * 8192 + 4096 + t * 8]);
    };

    const int xsw = l16 & 7;
    const int arow = (wm * 128 + l16) * 64;
    const int brow = (wn * 64 + l16) * 64;
    const int ac0 = ((0 + quad) ^ xsw) * 8;          // kk=0 granule offset
    const int ac1 = ((4 + quad) ^ xsw) * 8;          // kk=1

    auto ldA = [&](int buf, int mf, int kk) {
        return ld_frag(&As[buf][arow + mf * 1024 + (kk ? ac1 : ac0)]);
    };
    auto ldB = [&](int buf, int nf, int kk) {
        return ld_frag(&Bs[buf][brow + nf * 1024 + (kk ? ac1 : ac0)]);
    };

    f32x4 acc[8][4];
#pragma unroll
    for (int i = 0; i < 8; i++)
#pragma unroll
        for (int jj = 0; jj < 4; jj++) acc[i][jj] = f32x4{0.f, 0.f, 0.f, 0.f};

    const int NIT = K >> 6;
    // prologue: tile0 complete + tile1's {A0,B0,B1} in flight (A1(1) at P1 of
    // tt=0). 14 loads issued; vmcnt(6) keeps tile1's 6, drains tile0.
    stageA(0, 0, 0); stageA(0, 1, 0); stageB(0, 0, 0); stageB(0, 1, 0);
    stageA(1, 0, 64); stageB(1, 0, 64); stageB(1, 1, 64);
    VMCNT(6);
    BAR();

    bf16x8 al[4][2], ah[4][2], bl[2][2], bh[2][2];
    for (int tt = 0; tt < NIT; ++tt) {
        const int buf = tt & 1;
        const int k2 = (tt + 2) << 6;

        // ---- phase 1: (m-lo, n-lo). Read a-lo (8) + b-lo (4). Stage A1(t+1).
#pragma unroll
        for (int mt = 0; mt < 4; mt++) { al[mt][0] = ldA(buf, mt, 0); al[mt][1] = ldA(buf, mt, 1); }
#pragma unroll
        for (int nt = 0; nt < 2; nt++) { bl[nt][0] = ldB(buf, nt, 0); bl[nt][1] = ldB(buf, nt, 1); }
        if (tt + 1 < NIT) stageA(buf ^ 1, 1, (tt + 1) << 6);
        BAR(); LGKM0();
        __builtin_amdgcn_s_setprio(1);
#pragma unroll
        for (int mt = 0; mt < 4; mt++)
#pragma unroll
            for (int nt = 0; nt < 2; nt++)
#pragma unroll
                for (int kk = 0; kk < 2; kk++)
                    acc[mt][nt] = __builtin_amdgcn_mfma_f32_16x16x32_bf16(al[mt][kk], bl[nt][kk], acc[mt][nt], 0, 0, 0);
        __builtin_amdgcn_s_setprio(0);
        BAR();

        // ---- phase 2: (m-hi, n-lo). Read a-hi (8). b-lo from registers.
#pragma unroll
        for (int mt = 0; mt < 4; mt++) { ah[mt][0] = ldA(buf, 4 + mt, 0); ah[mt][1] = ldA(buf, 4 + mt, 1); }
        BAR(); LGKM0();
        __builtin_amdgcn_s_setprio(1);
#pragma unroll
        for (int mt = 0; mt < 4; mt++)
#pragma unroll
            for (int nt = 0; nt < 2; nt++)
#pragma unroll
                for (int kk = 0; kk < 2; kk++)
                    acc[4 + mt][nt] = __builtin_amdgcn_mfma_f32_16x16x32_bf16(ah[mt][kk], bl[nt][kk], acc[4 + mt][nt], 0, 0, 0);
        __builtin_amdgcn_s_setprio(0);
        BAR();

        // ---- phase 3: (m-lo, n-hi). Read b-hi (4). A fully read after P2 ->
        // stage A0(t+2). a-lo from registers.
#pragma unroll
        for (int nt = 0; nt < 2; nt++) { bh[nt][0] = ldB(buf, 2 + nt, 0); bh[nt][1] = ldB(buf, 2 + nt, 1); }
        if (tt + 2 < NIT) stageA(buf, 0, k2);
        BAR(); LGKM0();
        __builtin_amdgcn_s_setprio(1);
#pragma unroll
        for (int mt = 0; mt < 4; mt++)
#pragma unroll
            for (int nt = 0; nt < 2; nt++)
#pragma unroll
                for (int kk = 0; kk < 2; kk++)
                    acc[mt][2 + nt] = __builtin_amdgcn_mfma_f32_16x16x32_bf16(al[mt][kk], bh[nt][kk], acc[mt][2 + nt], 0, 0, 0);
        __builtin_amdgcn_s_setprio(0);
        BAR();

        // ---- phase 4: (m-hi, n-hi). B fully read after P3 -> stage B0+B1(t+2);
        // vmcnt(6) keeps exactly tile t+2's {A0,B0,B1}, drains tile t+1.
        if (tt + 2 < NIT)      { stageB(buf, 0, k2); stageB(buf, 1, k2); VMCNT(6); }
        else if (tt + 1 < NIT) { VMCNT(0); }
        BAR();
        __builtin_amdgcn_s_setprio(1);
#pragma unroll
        for (int mt = 0; mt < 4; mt++)
#pragma unroll
            for (int nt = 0; nt < 2; nt++)
#pragma unroll
                for (int kk = 0; kk < 2; kk++)
                    acc[4 + mt][2 + nt] = __builtin_amdgcn_mfma_f32_16x16x32_bf16(ah[mt][kk], bh[nt][kk], acc[4 + mt][2 + nt], 0, 0, 0);
        __builtin_amdgcn_s_setprio(0);
        BAR();
    }

#pragma unroll
    for (int mf = 0; mf < 8; mf++)
#pragma unroll
        for (int nf = 0; nf < 4; nf++) {
            const int row = bm + wm * 128 + mf * 16 + quad * 4;
            const int col = bn + wn * 64 + nf * 16 + l16;
#pragma unroll
            for (int rr = 0; rr < 4; rr++) {
                float v = acc[mf][nf][rr];
                if constexpr (sizeof(OutT) == 2)
                    C[(size_t)(row + rr) * N + col] = (OutT)f2bf(v);
                else
                    C[(size_t)(row + rr) * N + col] = v;
            }
        }
}

// ---------------------------------------------------------------- O-proj GEMM
// 256x128 tile, BK=64, 8 waves (4x2), wave = 64x64, 4 phases x 8 MFMA.
// (unchanged — verified round 6)
__global__ __launch_bounds__(512, 2) void gemm_o(const ushort_t* __restrict__ A,
                                                 const ushort_t* __restrict__ W,
                                                 float* __restrict__ C,
                                                 int N, int K) {
    __shared__ ushort_t As[2][256 * 64];             // 32 KB each
    __shared__ ushort_t Bs[2][128 * 64];             // 16 KB each
    const int t = threadIdx.x;
    const int lane = t & 63;
    const int quad = lane >> 4, l16 = lane & 15;
    const int wm = t >> 7, wn = (t >> 6) & 1;        // 4 x 2 wave grid

    int bid = blockIdx.x;
    int xcd = bid & 7, j = bid >> 3;
    const int tm = (xcd >> 1) * 4 + (j >> 3);
    const int tn = (xcd & 1) * 8 + (j & 7);
    const int bm = tm * 256, bn = tn * 128;

    const int srow0 = t >> 3;                        // rows 0..63
    const int sg0 = ((t & 7) ^ (srow0 & 7)) * 8;
    const int srow1 = srow0 + 64;                    // rows 64..127
    const int sg1 = ((t & 7) ^ (srow1 & 7)) * 8;

    auto stageA = [&](int buf, int half, int k0) {
        gload_lds16(A + (size_t)(bm + half * 128 + srow0) * K + k0 + sg0,
                    &As[buf][half * 8192 + t * 8]);
        gload_lds16(A + (size_t)(bm + half * 128 + srow1) * K + k0 + sg1,
                    &As[buf][half * 8192 + 4096 + t * 8]);
    };
    auto stageB = [&](int buf, int k0) {
        gload_lds16(W + (size_t)(bn + srow0) * K + k0 + sg0, &Bs[buf][t * 8]);
        gload_lds16(W + (size_t)(bn + srow1) * K + k0 + sg1, &Bs[buf][4096 + t * 8]);
    };

    const int xsw = l16 & 7;
    const int arow = (wm * 64 + l16) * 64;
    const int brow = (wn * 64 + l16) * 64;
    const int ac0 = ((0 + quad) ^ xsw) * 8;
    const int ac1 = ((4 + quad) ^ xsw) * 8;

    auto ldA = [&](int buf, int mf, int kk) {
        return ld_frag(&As[buf][arow + mf * 1024 + (kk ? ac1 : ac0)]);
    };
    auto ldB = [&](int buf, int nf, int kk) {
        return ld_frag(&Bs[buf][brow + nf * 1024 + (kk ? ac1 : ac0)]);
    };

    f32x4 acc[4][4];
#pragma unroll
    for (int i = 0; i < 4; i++)
#pragma unroll
        for (int jj = 0; jj < 4; jj++) acc[i][jj] = f32x4{0.f, 0.f, 0.f, 0.f};

    const int NIT = K >> 6;
    // prologue: tile0 (6 loads) + tile1 (6 loads); vmcnt(6) drains tile0.
    stageA(0, 0, 0); stageA(0, 1, 0); stageB(0, 0);
    stageA(1, 0, 64); stageA(1, 1, 64); stageB(1, 64);
    VMCNT(6);
    BAR();

    bf16x8 a[2][2], bl[2][2], bh[2][2];
    for (int tt = 0; tt < NIT; ++tt) {
        const int buf = tt & 1;
        const int k2 = (tt + 2) << 6;

        // ---- phase 1: (m-lo, n-lo). Read a-lo (4) + b-lo (4).
#pragma unroll
        for (int mt = 0; mt < 2; mt++) { a[mt][0] = ldA(buf, mt, 0); a[mt][1] = ldA(buf, mt, 1); }
#pragma unroll
        for (int nt = 0; nt < 2; nt++) { bl[nt][0] = ldB(buf, nt, 0); bl[nt][1] = ldB(buf, nt, 1); }
        BAR(); LGKM0();
        __builtin_amdgcn_s_setprio(1);
#pragma unroll
        for (int mt = 0; mt < 2; mt++)
#pragma unroll
            for (int nt = 0; nt < 2; nt++)
#pragma unroll
                for (int kk = 0; kk < 2; kk++)
                    acc[mt][nt] = __builtin_amdgcn_mfma_f32_16x16x32_bf16(a[mt][kk], bl[nt][kk], acc[mt][nt], 0, 0, 0);
        __builtin_amdgcn_s_setprio(0);
        BAR();

        // ---- phase 2: (m-lo, n-hi). Read b-hi (4).
#pragma unroll
        for (int nt = 0; nt < 2; nt++) { bh[nt][0] = ldB(buf, 2 + nt, 0); bh[nt][1] = ldB(buf, 2 + nt, 1); }
        BAR(); LGKM0();
        __builtin_amdgcn_s_setprio(1);
#pragma unroll
        for (int mt = 0; mt < 2; mt++)
#pragma unroll
            for (int nt = 0; nt < 2; nt++)
#pragma unroll
                for (int kk = 0; kk < 2; kk++)
                    acc[mt][2 + nt] = __builtin_amdgcn_mfma_f32_16x16x32_bf16(a[mt][kk], bh[nt][kk], acc[mt][2 + nt], 0, 0, 0);
        __builtin_amdgcn_s_setprio(0);
        BAR();

        // ---- phase 3: (m-hi, n-lo). Read a-hi (4). Stage B(t+2) (B drained @P2).
#pragma unroll
        for (int mt = 0; mt < 2; mt++) { a[mt][0] = ldA(buf, 2 + mt, 0); a[mt][1] = ldA(buf, 2 + mt, 1); }
        if (tt + 2 < NIT) stageB(buf, k2);
        BAR(); LGKM0();
        __builtin_amdgcn_s_setprio(1);
#pragma unroll
        for (int mt = 0; mt < 2; mt++)
#pragma unroll
            for (int nt = 0; nt < 2; nt++)
#pragma unroll
                for (int kk = 0; kk < 2; kk++)
                    acc[2 + mt][nt] = __builtin_amdgcn_mfma_f32_16x16x32_bf16(a[mt][kk], bl[nt][kk], acc[2 + mt][nt], 0, 0, 0);
        __builtin_amdgcn_s_setprio(0);
        BAR();

        // ---- phase 4: (m-hi, n-hi). Stage A0,A1(t+2) (A drained @P3); vmcnt(6).
        if (tt + 2 < NIT)      { stageA(buf, 0, k2); stageA(buf, 1, k2); VMCNT(6); }
        else if (tt + 1 < NIT) { VMCNT(0); }
        BAR();
        __builtin_amdgcn_s_setprio(1);
#pragma unroll
        for (int mt = 0; mt < 2; mt++)
#pragma unroll
            for (int nt = 0; nt < 2; nt++)
#pragma unroll
                for (int kk = 0; kk < 2; kk++)
                    acc[2 + mt][2 + nt] = __builtin_amdgcn_mfma_f32_16x16x32_bf16(a[mt][kk], bh[nt][kk], acc[2 + mt][2 + nt], 0, 0, 0);
        __builtin_amdgcn_s_setprio(0);
        BAR();
    }

#pragma unroll
    for (int mf = 0; mf < 4; mf++)
#pragma unroll
        for (int nf = 0; nf < 4; nf++) {
            const int row = bm + wm * 64 + mf * 16 + quad * 4;
            const int col = bn + wn * 64 + nf * 16 + l16;
#pragma unroll
            for (int rr = 0; rr < 4; rr++)
                C[(size_t)(row + rr) * N + col] = acc[mf][nf][rr];
        }
}

// ---------------------------------------------------------------- RoPE + l2norm
__global__ __launch_bounds__(256) void rope_norm(const ushort_t* __restrict__ qkv,
                                                 const float* __restrict__ cosb,
                                                 const float* __restrict__ sinb,
                                                 ushort_t* __restrict__ q,
                                                 ushort_t* __restrict__ k) {
    int row = blockIdx.x;                 // b*2048 + s
    int b = row >> 11, s = row & 2047;
    int w = threadIdx.x >> 6, lane = threadIdx.x & 63;
    int hh = blockIdx.y * 4 + w;          // 0..23
    const ushort_t* src = qkv + (size_t)row * 4096 + hh * 128;
    float x1 = bf2f(src[lane]);
    float x2 = bf2f(src[lane + 64]);
    float c = cosb[(size_t)row * 128 + lane];
    float sn = sinb[(size_t)row * 128 + lane];
    float y1 = x1 * c + x2 * sn;
    float y2 = x2 * c - x1 * sn;
    float ss = y1 * y1 + y2 * y2;
#pragma unroll
    for (int off = 1; off < 64; off <<= 1) ss += __shfl_xor(ss, off);
    float rinv = rsqrtf(ss * (1.0f / 128.0f) + 1e-6f);
    y1 *= rinv; y2 *= rinv;
    ushort_t* dst;
    if (hh < 16) dst = q + (((size_t)(b * 16 + hh)) * 2048 + s) * 128;
    else         dst = k + (((size_t)(b * 8 + hh - 16)) * 2048 + s) * 128;
    dst[lane] = f2bf(y1);
    dst[lane + 64] = f2bf(y2);
}

// ---------------------------------------------------------------- V transpose
__global__ __launch_bounds__(256) void v_transpose(const ushort_t* __restrict__ qkv,
                                                   ushort_t* __restrict__ vt) {
    __shared__ ushort_t tile[64 * 72];
    int t = threadIdx.x;
    int s0 = blockIdx.x * 64, d0 = blockIdx.y * 64, bh = blockIdx.z;
    int b = bh >> 3, kvh = bh & 7;
    {
        int sl = t >> 2, c = t & 3;
        const ushort_t* src = qkv + (size_t)(b * 2048 + s0 + sl) * 4096 + 3072 + kvh * 128 + d0 + c * 16;
        u32x4 v0 = *(const u32x4*)src;
        u32x4 v1 = *(const u32x4*)(src + 8);
        *(u32x4*)&tile[sl * 72 + c * 16] = v0;
        *(u32x4*)&tile[sl * 72 + c * 16 + 8] = v1;
    }
    __syncthreads();
    {
        int dl = t >> 2, c = t & 3;
        alignas(16) ushort_t tmp[16];
#pragma unroll
        for (int i = 0; i < 16; i++) tmp[i] = tile[(c * 16 + i) * 72 + dl];
        ushort_t* dst = vt + (size_t)(bh * 128 + d0 + dl) * 2048 + s0 + c * 16;
        *(u32x4*)dst = *(const u32x4*)&tmp[0];
        *(u32x4*)(dst + 8) = *(const u32x4*)&tmp[8];
    }
}

// ---------------------------------------------------------------- Flash attention
// v4 (unchanged, verified): 32x32 MFMA, swapped QK^T -> P lane-local; cvt_pk +
// permlane32_swap builds PV A-frag in registers. One barrier per iteration.
__global__ __launch_bounds__(512, 2) void flash_attn(const ushort_t* __restrict__ q,
                                                     const ushort_t* __restrict__ k,
                                                     const ushort_t* __restrict__ vt,
                                                     ushort_t* __restrict__ attn) {
    __shared__ ushort_t Ks[2][4 * 64 * 32];      // 2 x 16 KB  [qd][64 kv][32]
    __shared__ ushort_t Vts[2][2 * 128 * 32];    // 2 x 16 KB  [ks][128 d][32 kv]
    __shared__ float    Om[4][16][64][4];        // 64 KB o-merge scratch
    __shared__ float    Ls[2][4][32];            // lsum partials [wk][pid][qrow]
    const int t = threadIdx.x;
    const int w = t >> 6, lane = t & 63;
    const int wh = w & 1, chunk = (w >> 1) & 1, wk = w >> 2;
    const int pid = chunk * 2 + wh;
    const int l31 = lane & 31, hi = lane >> 5;
    const int swz = (l31 >> 1) & 3;
    const int lid = blockIdx.x;
    const int xcd = lid & 7, jj = lid >> 3;
    const int g = xcd * 2 + (jj >> 4);           // (b,kvh) group, 2 per XCD
    const int p = jj & 15;                       // q-tile pair index 0..15
    const int b = g >> 3, kvh = g & 7;
    const int h0 = kvh * 2;
    const size_t kbase = ((size_t)(b * 8 + kvh)) * 2048 * 128;
    const size_t vbase = ((size_t)(b * 8 + kvh)) * 128 * 2048;

    const float C1 = 0.12751744f;   // (1/sqrt(128)) * log2(e)
    const float C2 = 1.45f;         // fixed max in log2 domain

    auto stage = [&](int j0, int buf) {
#pragma unroll
        for (int i = 0; i < 2; i++) {            // K tile (16KB)
            int u = i * 512 + t;
            int qd = u >> 8, rr = (u >> 2) & 63;
            int c4 = ((u & 3) ^ ((rr >> 1) & 3)) * 8;
            gload_lds16(k + kbase + (size_t)(j0 + rr) * 128 + qd * 32 + c4,
                        (char*)Ks[buf] + u * 16);
        }
#pragma unroll
        for (int i = 0; i < 2; i++) {            // Vt tile (16KB)
            int u = i * 512 + t;
            int ks = u >> 9, dd = (u >> 2) & 127;
            int c4 = ((u & 3) ^ ((dd >> 1) & 3)) * 8;
            gload_lds16(vt + vbase + (size_t)dd * 2048 + j0 + ks * 32 + c4,
                        (char*)Vts[buf] + u * 16);
        }
    };

    const int qtile0 = 31 - p;                   // heavy pass first
    const int S_total = qtile0 + 1 + p + 1;      // tile-stream length (=33)
    auto j0_of = [&](int s) { return (s <= qtile0 ? s : s - qtile0 - 1) * 64; };

    stage(j0_of(0), 0);
    int sidx = 0;

    for (int pass = 0; pass < 2; ++pass) {
        const int qi = pass ? p : qtile0;
        const int q0 = qi * 64;
        const int hgl = h0 + wh;
        const int qg = q0 + chunk * 32 + l31;    // this lane's q-row (B side)

        bf16x8 qf[8];
        {
            const size_t qrow = ((size_t)(b * 16 + hgl) * 2048 + qg) * 128;
#pragma unroll
            for (int s = 0; s < 8; s++) {
                us8 v = *(const us8*)(q + qrow + s * 16 + hi * 8);
                qf[s] = __builtin_bit_cast(bf16x8, v);
            }
        }

        f32x16 o[4];
#pragma unroll
        for (int i = 0; i < 4; i++)
#pragma unroll
            for (int r = 0; r < 16; r++) o[i][r] = 0.f;
        float lsum = 0.f;

        for (int jt = 0; jt <= qi; ++jt) {
            const int j0 = jt * 64;
            const bool diag = (jt == qi);
            const int buf = sidx & 1;
            BARRIER_DRAIN();                     // drain own tile-sidx loads; tile visible
            if (sidx + 1 < S_total) stage(j0_of(sidx + 1), buf ^ 1);
            sidx++;

            // ---- QK^T swapped: sc = K(32kv) x Q(32q), k-dim = d = 128
            f32x16 sc;
#pragma unroll
            for (int r = 0; r < 16; r++) sc[r] = 0.f;
            __builtin_amdgcn_s_setprio(1);
#pragma unroll
            for (int s = 0; s < 8; s++) {
                bf16x8 kf = ld_frag(&Ks[buf][(s >> 1) * 2048 + (wk * 32 + l31) * 32 +
                                             (((((s & 1) << 1) | hi)) ^ swz) * 8]);
                sc = __builtin_amdgcn_mfma_f32_32x32x16_bf16(kf, qf[s], sc, 0, 0, 0);
            }
            __builtin_amdgcn_s_setprio(0);

            // ---- softmax in-register
#pragma unroll
            for (int r = 0; r < 16; r++)
                sc[r] = __builtin_amdgcn_exp2f(sc[r] * C1 - C2);
            if (diag) {
                const int kvb = j0 + wk * 32 + 4 * hi;
#pragma unroll
                for (int r = 0; r < 16; r++) {
                    int kg = kvb + (r & 3) + 8 * (r >> 2);
                    if (kg > qg) sc[r] = 0.f;
                }
            }
#pragma unroll
            for (int r = 0; r < 16; r++) lsum += sc[r];

            // ---- pack P -> PV A-frags via cvt_pk + permlane32_swap
            bf16x8 pf[2];
#pragma unroll
            for (int kp = 0; kp < 2; kp++) {
                const int rb = kp * 8;
                unsigned x0 = cvt_pk_bf16(sc[rb + 0], sc[rb + 1]);
                unsigned x1 = cvt_pk_bf16(sc[rb + 2], sc[rb + 3]);
                unsigned y0 = cvt_pk_bf16(sc[rb + 4], sc[rb + 5]);
                unsigned y1 = cvt_pk_bf16(sc[rb + 6], sc[rb + 7]);
                PERMSWAP(x0, y0);
                PERMSWAP(x1, y1);
                u32x4 pv; pv[0] = x0; pv[1] = x1; pv[2] = y0; pv[3] = y1;
                pf[kp] = __builtin_bit_cast(bf16x8, pv);
            }

            // ---- PV
            __builtin_amdgcn_s_setprio(1);
#pragma unroll
            for (int kp = 0; kp < 2; kp++)
#pragma unroll
                for (int od = 0; od < 4; od++) {
                    bf16x8 vf = ld_frag(&Vts[buf][wk * 4096 + (od * 32 + l31) * 32 +
                                                  ((((kp << 1) | hi)) ^ swz) * 8]);
                    o[od] = __builtin_amdgcn_mfma_f32_32x32x16_bf16(pf[kp], vf, o[od], 0, 0, 0);
                }
            __builtin_amdgcn_s_setprio(0);
        }

        // ---- pass epilogue: merge kv-halves, normalize, store
        lsum += __shfl_xor(lsum, 32);
        if (hi == 0) Ls[wk][pid][l31] = lsum;
        if (wk == 1) {
#pragma unroll
            for (int od = 0; od < 4; od++)
#pragma unroll
                for (int r4 = 0; r4 < 4; r4++) {
                    f32x4 v;
                    v[0] = o[od][r4 * 4 + 0]; v[1] = o[od][r4 * 4 + 1];
                    v[2] = o[od][r4 * 4 + 2]; v[3] = o[od][r4 * 4 + 3];
                    *(f32x4*)&Om[pid][od * 4 + r4][lane][0] = v;
                }
        }
        LGKM0();
        BAR();
        if (wk == 0) {
#pragma unroll
            for (int od = 0; od < 4; od++)
#pragma unroll
                for (int r4 = 0; r4 < 4; r4++) {
                    f32x4 m = *(const f32x4*)&Om[pid][od * 4 + r4][lane][0];
                    o[od][r4 * 4 + 0] += m[0]; o[od][r4 * 4 + 1] += m[1];
                    o[od][r4 * 4 + 2] += m[2]; o[od][r4 * 4 + 3] += m[3];
                }
            float rl[16];
#pragma unroll
            for (int r = 0; r < 16; r++) {
                int ql = (r & 3) + 8 * (r >> 2) + 4 * hi;
                rl[r] = 1.0f / (Ls[0][pid][ql] + Ls[1][pid][ql]);
            }
#pragma unroll
            for (int od = 0; od < 4; od++)
#pragma unroll
                for (int r = 0; r < 16; r++) {
                    int qg2 = q0 + chunk * 32 + (r & 3) + 8 * (r >> 2) + 4 * hi;
                    attn[(size_t)(b * 2048 + qg2) * 2048 + hgl * 128 + od * 32 + l31] =
                        f2bf(o[od][r] * rl[r]);
                }
        }
    }
}

// ---------------------------------------------------------------- launch
extern "C" void kernel_launch(void* const* d_in, const int* in_sizes, int n_in,
                              void* d_out, int out_size, void* d_ws, size_t ws_size,
                              hipStream_t stream) {
    (void)in_sizes; (void)n_in; (void)out_size; (void)ws_size;
    const float* hidden = (const float*)d_in[0];
    const float* cosb   = (const float*)d_in[1];
    const float* sinb   = (const float*)d_in[2];
    // d_in[3] = attention_mask: causal, computed inline
    const float* q_w    = (const float*)d_in[4];
    const float* k_w    = (const float*)d_in[5];
    const float* v_w    = (const float*)d_in[6];
    const float* o_w    = (const float*)d_in[7];

    char* ws = (char*)d_ws;                                  // 104 MB used
    ushort_t* hb   = (ushort_t*)(ws);                        // [4096][2048] bf16 hidden
    ushort_t* wqkv = (ushort_t*)(ws + (16ull << 20));        // [4096][2048] bf16 q|k|v weights
    ushort_t* owb  = (ushort_t*)(ws + (32ull << 20));        // [2048][2048] bf16 o_w
    ushort_t* qkv  = (ushort_t*)(ws + (40ull << 20));        // [4096][4096] bf16 qkv proj
    ushort_t* attn = qkv;                                    // alias: qkv consumed before flash
    ushort_t* qb   = (ushort_t*)(ws + (72ull << 20));        // [2][16][2048][128]
    ushort_t* kb   = (ushort_t*)(ws + (88ull << 20));        // [2][8][2048][128]
    ushort_t* vt   = (ushort_t*)(ws + (96ull << 20));        // [2][8][128][2048]

    convert_all<<<20480, 256, 0, stream>>>((const f32x4*)hidden, (const f32x4*)q_w,
                                           (const f32x4*)k_w, (const f32x4*)v_w,
                                           (const f32x4*)o_w,
                                           (us4*)hb, (us4*)wqkv, (us4*)owb);

    gemm256<ushort_t><<<256, 512, 0, stream>>>(hb, wqkv, qkv, 4096, 2048);
    rope_norm<<<dim3(4096, 6), 256, 0, stream>>>(qkv, cosb, sinb, qb, kb);
    v_transpose<<<dim3(32, 2, 16), 256, 0, stream>>>(qkv, vt);
    flash_attn<<<256, 512, 0, stream>>>(qb, kb, vt, attn);
    gemm_o<<<256, 512, 0, stream>>>(attn, owb, (float*)d_out, 2048, 2048);
}